// Round 18
// baseline (371.826 us; speedup 1.0000x reference)
//
#include <hip/hip_runtime.h>
#include <math.h>

typedef unsigned short u16;
typedef short s16x8 __attribute__((ext_vector_type(8)));
typedef float f32x4 __attribute__((ext_vector_type(4)));
typedef unsigned short u16x8 __attribute__((ext_vector_type(8)));
typedef unsigned short u16x4 __attribute__((ext_vector_type(4)));

#define DD 512

__device__ __forceinline__ float silu_f(float x) { return x / (1.f + __expf(-x)); }
__device__ __forceinline__ float gelu_f(float x) {
  float y = 1.5957691216f * (x + 0.044715f * x * x * x);
  return x / (1.f + __expf(-y));
}
__device__ __forceinline__ u16 f2bf(float f) {
  unsigned u = __float_as_uint(f);
  return (u16)((u + 0x7fffu + ((u >> 16) & 1u)) >> 16);
}
__device__ __forceinline__ float bf2f(u16 u) { return __uint_as_float(((unsigned)u) << 16); }
__device__ __forceinline__ unsigned cvtpk_bf16(float a, float b) {
  unsigned r;
  asm("v_cvt_pk_bf16_f32 %0, %1, %2" : "=v"(r) : "v"(a), "v"(b));
  return r;
}

__device__ __forceinline__ void gload16(const void* g, void* l) {
  __builtin_amdgcn_global_load_lds(
      (const __attribute__((address_space(1))) void*)(g),
      (__attribute__((address_space(3))) void*)(l), 16, 0, 0);
}

// ---------------- 64x64-tile bf16 GEMM, BK=64, XOR-swizzled LDS, 2-buf dbuf ----------------
// OB: 0 fp32 out (+res); 4 merged fp32 dual (N=1024); 3 merged QKV (N=1536);
//     1 plain bf16 out (ld=N); 5 bf16 out + fp32 res (ld=N);
//     6 bf16 out with fused per-64col softmax (head-aligned tiles, N==512, no-max exp)
template<int ACT, int OB>
__global__ __launch_bounds__(256) void gemm64(
    const u16* __restrict__ A, const u16* __restrict__ Bt,
    const float* __restrict__ bias, const float* __restrict__ res, float res_scale,
    float* __restrict__ outf, float* __restrict__ outf2,
    u16* __restrict__ outb, u16* __restrict__ outb2,
    int M, int N, int K)
{
  __shared__ u16 As[2][4096];
  __shared__ u16 Bs[2][4096];
  const int t = threadIdx.x, l = t & 63, w = t >> 6;
  const int gx = gridDim.x;
  const int nblk = gx * gridDim.y;
  const int id = blockIdx.y * gx + blockIdx.x;
  const int nid = (id & 7) * (nblk >> 3) + (id >> 3);
  const int bm = (nid / gx) << 6, bn = (nid % gx) << 6;
  const int wr = (w >> 1) << 5, wc = (w & 1) << 5;
  f32x4 acc[2][2];
#pragma unroll
  for (int i = 0; i < 2; ++i)
#pragma unroll
    for (int j = 0; j < 2; ++j) acc[i][j] = (f32x4){0.f, 0.f, 0.f, 0.f};

  auto stage = [&](int k0, int buf) {
#pragma unroll
    for (int i = 0; i < 2; ++i) {
      int c = t + (i << 8);
      int row = c >> 3, cq = c & 7;
      int cs = cq ^ (row & 7);
      gload16(A + (size_t)(bm + row) * K + k0 + cs * 8, (char*)As[buf] + (i << 12) + (w << 10));
      gload16(Bt + (size_t)(bn + row) * K + k0 + cs * 8, (char*)Bs[buf] + (i << 12) + (w << 10));
    }
  };
  stage(0, 0);
  asm volatile("s_waitcnt vmcnt(0)" ::: "memory");
  __builtin_amdgcn_s_barrier();

  const int fr = l & 15, q0 = l >> 4;
  const int nk = K >> 6;
  int cur = 0;
  for (int kt = 0; kt < nk; ++kt) {
    if (kt + 1 < nk) stage((kt + 1) << 6, cur ^ 1);
    s16x8 af[2][2], bg[2][2];
#pragma unroll
    for (int kk = 0; kk < 2; ++kk)
#pragma unroll
      for (int i = 0; i < 2; ++i) {
        int ra = wr + i * 16 + fr;
        af[kk][i] = *(const s16x8*)&As[cur][ra * 64 + (((q0 + kk * 4)) ^ (ra & 7)) * 8];
        int rb = wc + i * 16 + fr;
        bg[kk][i] = *(const s16x8*)&Bs[cur][rb * 64 + (((q0 + kk * 4)) ^ (rb & 7)) * 8];
      }
    asm volatile("s_waitcnt lgkmcnt(0)" ::: "memory");
    __builtin_amdgcn_sched_barrier(0);
#pragma unroll
    for (int kk = 0; kk < 2; ++kk)
#pragma unroll
      for (int mi = 0; mi < 2; ++mi)
#pragma unroll
        for (int ni = 0; ni < 2; ++ni)
          acc[mi][ni] = __builtin_amdgcn_mfma_f32_16x16x32_bf16(af[kk][mi], bg[kk][ni], acc[mi][ni], 0, 0, 0);
    asm volatile("s_waitcnt vmcnt(0)" ::: "memory");
    __builtin_amdgcn_s_barrier();
    cur ^= 1;
  }

  const int cr0 = (l >> 4) << 2, cc = l & 15;

  if (OB == 0 || OB == 4) {
    float* fdst = outf;
    int coff = bn, ld = N;
    if (OB == 4) { ld = 512; coff = bn & 511; if (bn >= 512) fdst = outf2; }
#pragma unroll
    for (int ni = 0; ni < 2; ++ni) {
      int n = bn + wc + ni * 16 + cc;
      int col = coff + wc + ni * 16 + cc;
      float bia = bias[n];
#pragma unroll
      for (int mi = 0; mi < 2; ++mi) {
#pragma unroll
        for (int r = 0; r < 4; ++r) {
          int m = bm + wr + mi * 16 + cr0 + r;
          size_t off = (size_t)m * ld + col;
          float o = acc[mi][ni][r] + bia;
          if (ACT == 1) o = gelu_f(o);
          if (res) o = fmaf(res_scale, res[off], o);
          fdst[off] = o;
        }
      }
    }
  } else if (OB == 1 || OB == 5) {
#pragma unroll
    for (int ni = 0; ni < 2; ++ni) {
      int n = bn + wc + ni * 16 + cc;
      float bia = bias[n];
#pragma unroll
      for (int mi = 0; mi < 2; ++mi) {
#pragma unroll
        for (int r = 0; r < 4; ++r) {
          int m = bm + wr + mi * 16 + cr0 + r;
          size_t off = (size_t)m * N + n;
          float o = acc[mi][ni][r] + bia;
          if (ACT == 1) o = gelu_f(o);
          if (OB == 5) o = fmaf(res_scale, res[off], o);
          outb[off] = f2bf(o);
        }
      }
    }
  } else if (OB == 6) {
    // fused head softmax -> bf16: tile's 64 cols == one head's softmax range.
    float* smem = (float*)&As[0][0];      // 128 floats
    float ev[2][2][4];
    float part[2][4];
#pragma unroll
    for (int mi = 0; mi < 2; ++mi)
#pragma unroll
      for (int r = 0; r < 4; ++r) part[mi][r] = 0.f;
#pragma unroll
    for (int ni = 0; ni < 2; ++ni) {
      float bia = bias[bn + wc + ni * 16 + cc];
#pragma unroll
      for (int mi = 0; mi < 2; ++mi)
#pragma unroll
        for (int r = 0; r < 4; ++r) {
          float e = __expf(acc[mi][ni][r] + bia);
          ev[mi][ni][r] = e;
          part[mi][r] += e;
        }
    }
#pragma unroll
    for (int mi = 0; mi < 2; ++mi)
#pragma unroll
      for (int r = 0; r < 4; ++r) {
        float s = part[mi][r];
        s += __shfl_xor(s, 1); s += __shfl_xor(s, 2);
        s += __shfl_xor(s, 4); s += __shfl_xor(s, 8);
        part[mi][r] = s;
      }
    __syncthreads();
#pragma unroll
    for (int mi = 0; mi < 2; ++mi)
#pragma unroll
      for (int r = 0; r < 4; ++r) {
        int trow = wr + mi * 16 + cr0 + r;
        smem[(w & 1) * 64 + trow] = part[mi][r];
      }
    __syncthreads();
#pragma unroll
    for (int mi = 0; mi < 2; ++mi)
#pragma unroll
      for (int r = 0; r < 4; ++r) {
        int trow = wr + mi * 16 + cr0 + r;
        float inv = 1.f / (smem[trow] + smem[64 + trow]);
#pragma unroll
        for (int ni = 0; ni < 2; ++ni) {
          int n = bn + wc + ni * 16 + cc;
          outb[(size_t)(bm + trow) * 512 + n] = f2bf(ev[mi][ni][r] * inv);
        }
      }
  } else {
    // OB == 3: merged QKV
    int seg = bn >> 9;
    int colbase = bn & 511;
    if (seg < 2) {
      u16* dst = seg ? outb2 : outb;
#pragma unroll
      for (int ni = 0; ni < 2; ++ni) {
        int col = colbase + wc + ni * 16 + cc;
        float bia = bias[bn + wc + ni * 16 + cc];
#pragma unroll
        for (int mi = 0; mi < 2; ++mi) {
#pragma unroll
          for (int r = 0; r < 4; ++r) {
            int m = bm + wr + mi * 16 + cr0 + r;
            dst[(size_t)m * 512 + col] = f2bf(acc[mi][ni][r] + bia);
          }
        }
      }
    } else {
      u16* tile = &As[0][0];
      __syncthreads();
#pragma unroll
      for (int ni = 0; ni < 2; ++ni) {
        int lc = wc + ni * 16 + cc;
        float bia = bias[bn + wc + ni * 16 + cc];
#pragma unroll
        for (int mi = 0; mi < 2; ++mi) {
          int lm0 = wr + mi * 16 + cr0;
          u16x4 pk;
#pragma unroll
          for (int r = 0; r < 4; ++r) pk[r] = f2bf(acc[mi][ni][r] + bia);
          *(u16x4*)&tile[lc * 64 + (lm0 ^ ((lc & 7) << 3))] = pk;
        }
      }
      __syncthreads();
      int h = colbase >> 6;
      size_t vrow0 = ((size_t)((bm >> 10) * 8 + h)) * 64;
      int d = t >> 3, c8 = (t & 7) << 3;
      *(u16x8*)(((u16*)outf) + (vrow0 + d) * 1024 + (bm & 1023) + c8) =
          *(u16x8*)&tile[d * 64 + (c8 ^ ((d & 7) << 3))];
    }
  }
}

// ---------------- 8-wave 128x256 tile GEMM (W1), BK=32, 4-chunk XOR swizzle ----------------
template<int ACT, int OBF>
__global__ __launch_bounds__(512) void gemm8w(
    const u16* __restrict__ A, const u16* __restrict__ Bt,
    const float* __restrict__ bias, float* __restrict__ outf, u16* __restrict__ outb,
    int M, int N, int K)
{
  __shared__ u16 As[2][4096];
  __shared__ u16 Bs[2][8192];
  const int t = threadIdx.x, l = t & 63, w = t >> 6;
  const int gx = gridDim.x;
  const int nblk = gx * gridDim.y;
  const int id = blockIdx.y * gx + blockIdx.x;
  const int nid = (id & 7) * (nblk >> 3) + (id >> 3);
  const int bm = (nid / gx) << 7, bn = (nid % gx) << 8;
  const int wr = (w >> 2) << 6, wc = (w & 3) << 6;
  f32x4 acc[4][4];
#pragma unroll
  for (int i = 0; i < 4; ++i)
#pragma unroll
    for (int j = 0; j < 4; ++j) acc[i][j] = (f32x4){0.f, 0.f, 0.f, 0.f};

  auto stage = [&](int k0, int buf) {
    {
      int row = t >> 2, cq = t & 3;
      int cs = cq ^ ((row >> 1) & 3);
      gload16(A + (size_t)(bm + row) * K + k0 + cs * 8, (char*)As[buf] + (w << 10));
    }
#pragma unroll
    for (int i = 0; i < 2; ++i) {
      int c = t + (i << 9);
      int row = c >> 2, cq = c & 3;
      int cs = cq ^ ((row >> 1) & 3);
      gload16(Bt + (size_t)(bn + row) * K + k0 + cs * 8, (char*)Bs[buf] + ((w + (i << 3)) << 10));
    }
  };
  stage(0, 0);
  asm volatile("s_waitcnt vmcnt(0)" ::: "memory");
  __builtin_amdgcn_s_barrier();

  const int fr = l & 15, q0 = l >> 4;
  const int nk = K >> 5;
  int cur = 0;
  for (int kt = 0; kt < nk; ++kt) {
    if (kt + 1 < nk) stage((kt + 1) << 5, cur ^ 1);
    s16x8 af[4], bg[4];
#pragma unroll
    for (int i = 0; i < 4; ++i) {
      int ra = wr + i * 16 + fr;
      af[i] = *(const s16x8*)&As[cur][ra * 32 + (q0 ^ ((ra >> 1) & 3)) * 8];
      int rb = wc + i * 16 + fr;
      bg[i] = *(const s16x8*)&Bs[cur][rb * 32 + (q0 ^ ((rb >> 1) & 3)) * 8];
    }
    asm volatile("s_waitcnt lgkmcnt(0)" ::: "memory");
    __builtin_amdgcn_sched_barrier(0);
#pragma unroll
    for (int mi = 0; mi < 4; ++mi)
#pragma unroll
      for (int ni = 0; ni < 4; ++ni)
        acc[mi][ni] = __builtin_amdgcn_mfma_f32_16x16x32_bf16(af[mi], bg[ni], acc[mi][ni], 0, 0, 0);
    asm volatile("s_waitcnt vmcnt(0)" ::: "memory");
    __builtin_amdgcn_s_barrier();
    cur ^= 1;
  }

  const int cr0 = (l >> 4) << 2, cc = l & 15;
#pragma unroll
  for (int ni = 0; ni < 4; ++ni) {
    int n = bn + wc + ni * 16 + cc;
    float bia = bias[n];
#pragma unroll
    for (int mi = 0; mi < 4; ++mi) {
#pragma unroll
      for (int r = 0; r < 4; ++r) {
        int m = bm + wr + mi * 16 + cr0 + r;
        size_t off = (size_t)m * N + n;
        float o = acc[mi][ni][r] + bia;
        if (ACT == 1) o = gelu_f(o);
        if (OBF) outb[off] = f2bf(o);
        else outf[off] = o;
      }
    }
  }
}

// ---------------- xf projection ----------------
__global__ __launch_bounds__(256) void xfp_k(
    const float* __restrict__ xf, const u16* __restrict__ apwT,
    const float* __restrict__ bias, float* __restrict__ xfp)
{
  int wid = blockIdx.x * 4 + (threadIdx.x >> 6);
  int lane = threadIdx.x & 63;
  int b = wid >> 8, n = wid & 255;
  const u16* wp = apwT + (size_t)n * 768;
  const float* xp = xf + (size_t)b * 768;
  float s = 0.f;
#pragma unroll
  for (int j = 0; j < 12; ++j) s = fmaf(xp[lane + j * 64], bf2f(wp[lane + j * 64]), s);
#pragma unroll
  for (int m = 1; m < 64; m <<= 1) s += __shfl_xor(s, m);
  if (lane == 0) xfp[wid] = s + bias[n];
}

// ---------------- concat biases ----------------
__global__ __launch_bounds__(256) void biascat_k(
    const float* __restrict__ qb, const float* __restrict__ kb, const float* __restrict__ vb,
    const float* __restrict__ ckb, const float* __restrict__ cvb,
    float* __restrict__ bQKV, float* __restrict__ bKV)
{
  int t = blockIdx.x * 256 + threadIdx.x;
  if (t < 512) bQKV[t] = qb[t];
  else if (t < 1024) bQKV[t] = kb[t - 512];
  else if (t < 1536) bQKV[t] = vb[t - 1024];
  else if (t < 2048) bKV[t - 1536] = ckb[t - 1536];
  else if (t < 2560) bKV[t - 1536] = cvb[t - 2048];
}

// ---------------- LayerNorm over D=512, fp32 input ----------------
__global__ __launch_bounds__(256) void ln_k(
    const float* __restrict__ src, const float* __restrict__ g,
    const float* __restrict__ b, float* __restrict__ out32, u16* __restrict__ out16,
    int rows, int do_silu)
{
  int lane = threadIdx.x & 63, wv = threadIdx.x >> 6;
  int row = (blockIdx.x << 2) + wv;
  if (row >= rows) return;
  const float* p = src + (size_t)row * DD;
  float4 v0 = *(const float4*)(p + lane * 4);
  float4 v1 = *(const float4*)(p + 256 + lane * 4);
  float s = v0.x + v0.y + v0.z + v0.w + v1.x + v1.y + v1.z + v1.w;
  float ss = v0.x*v0.x + v0.y*v0.y + v0.z*v0.z + v0.w*v0.w
           + v1.x*v1.x + v1.y*v1.y + v1.z*v1.z + v1.w*v1.w;
#pragma unroll
  for (int m = 1; m < 64; m <<= 1) { s += __shfl_xor(s, m); ss += __shfl_xor(ss, m); }
  float mean = s * (1.f / 512.f);
  float var = ss * (1.f / 512.f) - mean * mean;
  float rstd = rsqrtf(var + 1e-5f);
  float4 g0 = *(const float4*)(g + lane * 4);
  float4 g1 = *(const float4*)(g + 256 + lane * 4);
  float4 b0 = *(const float4*)(b + lane * 4);
  float4 b1 = *(const float4*)(b + 256 + lane * 4);
  float o[8];
  o[0] = (v0.x - mean) * rstd * g0.x + b0.x;
  o[1] = (v0.y - mean) * rstd * g0.y + b0.y;
  o[2] = (v0.z - mean) * rstd * g0.z + b0.z;
  o[3] = (v0.w - mean) * rstd * g0.w + b0.w;
  o[4] = (v1.x - mean) * rstd * g1.x + b1.x;
  o[5] = (v1.y - mean) * rstd * g1.y + b1.y;
  o[6] = (v1.z - mean) * rstd * g1.z + b1.z;
  o[7] = (v1.w - mean) * rstd * g1.w + b1.w;
  if (do_silu) {
#pragma unroll
    for (int j = 0; j < 8; ++j) o[j] = silu_f(o[j]);
  }
  if (out32) {
    *(float4*)(out32 + (size_t)row * DD + lane * 4) = make_float4(o[0], o[1], o[2], o[3]);
    *(float4*)(out32 + (size_t)row * DD + 256 + lane * 4) = make_float4(o[4], o[5], o[6], o[7]);
  }
  if (out16) {
    u16x4 h0, h1;
#pragma unroll
    for (int j = 0; j < 4; ++j) { h0[j] = f2bf(o[j]); h1[j] = f2bf(o[4 + j]); }
    *(u16x4*)(out16 + (size_t)row * DD + lane * 4) = h0;
    *(u16x4*)(out16 + (size_t)row * DD + 256 + lane * 4) = h1;
  }
}

// ---------------- LayerNorm over D=512, bf16 input ----------------
__global__ __launch_bounds__(256) void lnb_k(
    const u16* __restrict__ src, const float* __restrict__ g,
    const float* __restrict__ b, float* __restrict__ out32, u16* __restrict__ out16,
    int rows, int do_silu)
{
  int lane = threadIdx.x & 63, wv = threadIdx.x >> 6;
  int row = (blockIdx.x << 2) + wv;
  if (row >= rows) return;
  const u16* p = src + (size_t)row * DD;
  u16x4 a0 = *(const u16x4*)(p + lane * 4);
  u16x4 a1 = *(const u16x4*)(p + 256 + lane * 4);
  float v[8];
#pragma unroll
  for (int j = 0; j < 4; ++j) { v[j] = bf2f(a0[j]); v[4 + j] = bf2f(a1[j]); }
  float s = 0.f, ss = 0.f;
#pragma unroll
  for (int j = 0; j < 8; ++j) { s += v[j]; ss = fmaf(v[j], v[j], ss); }
#pragma unroll
  for (int m = 1; m < 64; m <<= 1) { s += __shfl_xor(s, m); ss += __shfl_xor(ss, m); }
  float mean = s * (1.f / 512.f);
  float var = ss * (1.f / 512.f) - mean * mean;
  float rstd = rsqrtf(var + 1e-5f);
  float4 g0 = *(const float4*)(g + lane * 4);
  float4 g1 = *(const float4*)(g + 256 + lane * 4);
  float4 b0 = *(const float4*)(b + lane * 4);
  float4 b1 = *(const float4*)(b + 256 + lane * 4);
  float o[8];
  o[0] = (v[0] - mean) * rstd * g0.x + b0.x;
  o[1] = (v[1] - mean) * rstd * g0.y + b0.y;
  o[2] = (v[2] - mean) * rstd * g0.z + b0.z;
  o[3] = (v[3] - mean) * rstd * g0.w + b0.w;
  o[4] = (v[4] - mean) * rstd * g1.x + b1.x;
  o[5] = (v[5] - mean) * rstd * g1.y + b1.y;
  o[6] = (v[6] - mean) * rstd * g1.z + b1.z;
  o[7] = (v[7] - mean) * rstd * g1.w + b1.w;
  if (do_silu) {
#pragma unroll
    for (int j = 0; j < 8; ++j) o[j] = silu_f(o[j]);
  }
  if (out32) {
    *(float4*)(out32 + (size_t)row * DD + lane * 4) = make_float4(o[0], o[1], o[2], o[3]);
    *(float4*)(out32 + (size_t)row * DD + 256 + lane * 4) = make_float4(o[4], o[5], o[6], o[7]);
  }
  if (out16) {
    u16x4 h0, h1;
#pragma unroll
    for (int j = 0; j < 4; ++j) { h0[j] = f2bf(o[j]); h1[j] = f2bf(o[4 + j]); }
    *(u16x4*)(out16 + (size_t)row * DD + lane * 4) = h0;
    *(u16x4*)(out16 + (size_t)row * DD + 256 + lane * 4) = h1;
  }
}

// ---------------- fused double-LN ----------------
__global__ __launch_bounds__(256) void ln2_k(
    const u16* __restrict__ src, const float* __restrict__ g1, const float* __restrict__ b1,
    const float* __restrict__ g2, const float* __restrict__ b2,
    float* __restrict__ out1, u16* __restrict__ out2, int rows)
{
  int lane = threadIdx.x & 63, wv = threadIdx.x >> 6;
  int row = (blockIdx.x << 2) + wv;
  if (row >= rows) return;
  const u16* p = src + (size_t)row * DD;
  u16x4 a0 = *(const u16x4*)(p + lane * 4);
  u16x4 a1 = *(const u16x4*)(p + 256 + lane * 4);
  float v[8];
#pragma unroll
  for (int j = 0; j < 4; ++j) { v[j] = bf2f(a0[j]); v[4 + j] = bf2f(a1[j]); }
  float s = 0.f, ss = 0.f;
#pragma unroll
  for (int j = 0; j < 8; ++j) { s += v[j]; ss = fmaf(v[j], v[j], ss); }
#pragma unroll
  for (int m = 1; m < 64; m <<= 1) { s += __shfl_xor(s, m); ss += __shfl_xor(ss, m); }
  float mean = s * (1.f / 512.f);
  float rstd = rsqrtf(ss * (1.f / 512.f) - mean * mean + 1e-5f);
  float4 G0 = *(const float4*)(g1 + lane * 4);
  float4 G1 = *(const float4*)(g1 + 256 + lane * 4);
  float4 B0 = *(const float4*)(b1 + lane * 4);
  float4 B1 = *(const float4*)(b1 + 256 + lane * 4);
  float y[8];
  y[0] = (v[0] - mean) * rstd * G0.x + B0.x;
  y[1] = (v[1] - mean) * rstd * G0.y + B0.y;
  y[2] = (v[2] - mean) * rstd * G0.z + B0.z;
  y[3] = (v[3] - mean) * rstd * G0.w + B0.w;
  y[4] = (v[4] - mean) * rstd * G1.x + B1.x;
  y[5] = (v[5] - mean) * rstd * G1.y + B1.y;
  y[6] = (v[6] - mean) * rstd * G1.z + B1.z;
  y[7] = (v[7] - mean) * rstd * G1.w + B1.w;
  *(float4*)(out1 + (size_t)row * DD + lane * 4) = make_float4(y[0], y[1], y[2], y[3]);
  *(float4*)(out1 + (size_t)row * DD + 256 + lane * 4) = make_float4(y[4], y[5], y[6], y[7]);
  float s2 = 0.f, ss2 = 0.f;
#pragma unroll
  for (int j = 0; j < 8; ++j) { s2 += y[j]; ss2 = fmaf(y[j], y[j], ss2); }
#pragma unroll
  for (int m = 1; m < 64; m <<= 1) { s2 += __shfl_xor(s2, m); ss2 += __shfl_xor(ss2, m); }
  float m2 = s2 * (1.f / 512.f);
  float r2 = rsqrtf(ss2 * (1.f / 512.f) - m2 * m2 + 1e-5f);
  float4 H0 = *(const float4*)(g2 + lane * 4);
  float4 H1 = *(const float4*)(g2 + 256 + lane * 4);
  float4 C0 = *(const float4*)(b2 + lane * 4);
  float4 C1 = *(const float4*)(b2 + 256 + lane * 4);
  u16x4 h0, h1;
  h0[0] = f2bf((y[0] - m2) * r2 * H0.x + C0.x);
  h0[1] = f2bf((y[1] - m2) * r2 * H0.y + C0.y);
  h0[2] = f2bf((y[2] - m2) * r2 * H0.z + C0.z);
  h0[3] = f2bf((y[3] - m2) * r2 * H0.w + C0.w);
  h1[0] = f2bf((y[4] - m2) * r2 * H1.x + C1.x);
  h1[1] = f2bf((y[5] - m2) * r2 * H1.y + C1.y);
  h1[2] = f2bf((y[6] - m2) * r2 * H1.z + C1.z);
  h1[3] = f2bf((y[7] - m2) * r2 * H1.w + C1.w);
  *(u16x4*)(out2 + (size_t)row * DD + lane * 4) = h0;
  *(u16x4*)(out2 + (size_t)row * DD + 256 + lane * 4) = h1;
}

// ---------------- MFMA flash self-attention v4: no KV LDS (L2-resident direct fragments),
// barrier-free K/V loop, LDS = Q/P region only (16.5KB) ----------------
__global__ __launch_bounds__(256) void attn4_k(
    const u16* __restrict__ q, const u16* __restrict__ k,
    const u16* __restrict__ vt, u16* __restrict__ out)
{
  __shared__ __align__(16) char QP[16384];
  __shared__ float Lr[4][32];

  const int t = threadIdx.x, l = t & 63, w = t >> 6;
  const int id = blockIdx.x;
  const int blk = (id & 7) * 64 + (id >> 3);   // chunked XCD swizzle: one batch per XCD
  const int qt = blk & 7, h = (blk >> 3) & 7, b = blk >> 6;
  const size_t qbase = ((size_t)(b * 1024 + qt * 128)) * 512 + h * 64;
  const size_t kbase = ((size_t)(b * 1024)) * 512 + h * 64;
  const size_t vbase = ((size_t)((b * 8 + h) * 64)) * 1024;

  // stage Q tile [128][64] swizzled into QP
#pragma unroll
  for (int i = 0; i < 4; ++i) {
    int chunk = i * 256 + w * 64 + l;
    int row = chunk >> 3, c = chunk & 7;
    int cs = c ^ (row & 7);
    gload16(q + qbase + (size_t)row * 512 + cs * 8, QP + (i * 256 + w * 64) * 16);
  }
  asm volatile("s_waitcnt vmcnt(0)" ::: "memory");
  __builtin_amdgcn_s_barrier();

  s16x8 qf[2][2];
#pragma unroll
  for (int ti = 0; ti < 2; ++ti)
#pragma unroll
    for (int kk = 0; kk < 2; ++kk) {
      int row = w * 32 + ti * 16 + (l & 15);
      int ch = ((l >> 4) + kk * 4) ^ (row & 7);
      qf[ti][kk] = *(const s16x8*)(QP + row * 128 + ch * 16);
    }
  asm volatile("s_waitcnt lgkmcnt(0)" ::: "memory");
  __builtin_amdgcn_s_barrier();   // all waves done reading Q region before P overwrites

  f32x4 oacc[2][4];
#pragma unroll
  for (int qi = 0; qi < 2; ++qi)
#pragma unroll
    for (int dj = 0; dj < 4; ++dj) oacc[qi][dj] = (f32x4){0.f, 0.f, 0.f, 0.f};
  float lsum[2] = {0.f, 0.f};

  const int fr16 = l & 15, q16 = l >> 4;

  for (int st = 0; st < 16; ++st) {
    // ---- S^T = K @ Q^T, K fragments direct from global (L2-resident) ----
    f32x4 sacc[4][2];
#pragma unroll
    for (int si = 0; si < 4; ++si)
#pragma unroll
      for (int ti = 0; ti < 2; ++ti) sacc[si][ti] = (f32x4){0.f, 0.f, 0.f, 0.f};
#pragma unroll
    for (int si = 0; si < 4; ++si) {
      const u16* kp = k + kbase + (size_t)(st * 64 + si * 16 + fr16) * 512 + q16 * 8;
      s16x8 kf0 = *(const s16x8*)(kp);
      s16x8 kf1 = *(const s16x8*)(kp + 32);
#pragma unroll
      for (int ti = 0; ti < 2; ++ti) {
        sacc[si][ti] = __builtin_amdgcn_mfma_f32_16x16x32_bf16(kf0, qf[ti][0], sacc[si][ti], 0, 0, 0);
        sacc[si][ti] = __builtin_amdgcn_mfma_f32_16x16x32_bf16(kf1, qf[ti][1], sacc[si][ti], 0, 0, 0);
      }
    }
    // ---- P = exp(S/8) -> per-wave LDS region (swizzled) ----
#pragma unroll
    for (int si = 0; si < 4; ++si)
#pragma unroll
      for (int ti = 0; ti < 2; ++ti) {
        float e0 = __expf(sacc[si][ti][0] * 0.125f);
        float e1 = __expf(sacc[si][ti][1] * 0.125f);
        float e2 = __expf(sacc[si][ti][2] * 0.125f);
        float e3 = __expf(sacc[si][ti][3] * 0.125f);
        lsum[ti] += (e0 + e1) + (e2 + e3);
        uint2 pk2;
        pk2.x = cvtpk_bf16(e0, e1);
        pk2.y = cvtpk_bf16(e2, e3);
        int tl = ti * 16 + (l & 15);
        int sb = (si * 16 + (l >> 4) * 4) * 2;
        *(uint2*)(QP + w * 4096 + tl * 128 + (sb ^ ((tl & 7) << 4))) = pk2;
      }
    // ---- O += P @ V, V fragments direct from global ----
#pragma unroll
    for (int kk = 0; kk < 2; ++kk) {
      s16x8 pf[2];
#pragma unroll
      for (int qi = 0; qi < 2; ++qi) {
        int tl = qi * 16 + (l & 15);
        int ch = ((l >> 4) + kk * 4) ^ (tl & 7);
        pf[qi] = *(const s16x8*)(QP + w * 4096 + tl * 128 + ch * 16);
      }
#pragma unroll
      for (int dj = 0; dj < 4; ++dj) {
        const u16* vp = vt + vbase + (size_t)(dj * 16 + fr16) * 1024 + st * 64 + (q16 + kk * 4) * 8;
        s16x8 vf = *(const s16x8*)(vp);
#pragma unroll
        for (int qi = 0; qi < 2; ++qi)
          oacc[qi][dj] = __builtin_amdgcn_mfma_f32_16x16x32_bf16(pf[qi], vf, oacc[qi][dj], 0, 0, 0);
      }
    }
  }

#pragma unroll
  for (int ti = 0; ti < 2; ++ti) {
    lsum[ti] += __shfl_xor(lsum[ti], 16);
    lsum[ti] += __shfl_xor(lsum[ti], 32);
    Lr[w][ti * 16 + (l & 15)] = lsum[ti];
  }
  // per-wave Lr region; in-wave LDS ordering + wave-uniform read after write
  asm volatile("s_waitcnt lgkmcnt(0)" ::: "memory");
  u16* otile = (u16*)QP;
#pragma unroll
  for (int qi = 0; qi < 2; ++qi) {
    float linv[4];
#pragma unroll
    for (int r = 0; r < 4; ++r) linv[r] = 1.f / Lr[w][qi * 16 + (l >> 4) * 4 + r];
#pragma unroll
    for (int dj = 0; dj < 4; ++dj) {
#pragma unroll
      for (int r = 0; r < 4; ++r) {
        int trl = w * 32 + qi * 16 + (l >> 4) * 4 + r;
        otile[trl * 64 + dj * 16 + (l & 15)] = f2bf(silu_f(oacc[qi][dj][r] * linv[r]));
      }
    }
  }
  __syncthreads();
#pragma unroll
  for (int p = 0; p < 4; ++p) {
    int flat = p * 256 + t;
    int row = flat >> 3, c8 = (flat & 7) << 3;
    *(u16x8*)(out + ((size_t)(b * 1024 + qt * 128 + row)) * 512 + h * 64 + c8) =
        *(u16x8*)&otile[row * 64 + c8];
  }
}

// ---------------- merged seq-softmax: blocks 0..255 -> ck (NL=512), 256..511 -> sk (NL=256) ----------------
__device__ __forceinline__ void smseq_body(float* p, int b, int cg, int NL, int nj, int ci, float* red, int t)
{
  int col = cg * 16 + ci;
  float vals[32];
  float s = 0.f;
  int nit = NL / 16;
  for (int j = 0; j < nit; ++j) {
    float x = __expf(p[((size_t)(b * NL) + nj + j * 16) * 512 + col]);
    vals[j] = x; s += x;
  }
  red[t] = s;
  __syncthreads();
  float tot = 0.f;
#pragma unroll
  for (int j = 0; j < 16; ++j) tot += red[ci + j * 16];
  float inv = 1.f / tot;
  for (int j = 0; j < nit; ++j)
    p[((size_t)(b * NL) + nj + j * 16) * 512 + col] = vals[j] * inv;
}

__global__ __launch_bounds__(256) void smseq2_k(float* __restrict__ ck, float* __restrict__ sk)
{
  __shared__ float red[256];
  int t = threadIdx.x;
  int ci = t & 15, nj = t >> 4;
  if (blockIdx.x < 256) {
    int b = blockIdx.x >> 5, cg = blockIdx.x & 31;
    smseq_body(ck, b, cg, 512, nj, ci, red, t);
  } else {
    int blk = blockIdx.x - 256;
    int b = blk >> 5, cg = blk & 31;
    smseq_body(sk, b, cg, 256, nj, ci, red, t);
  }
}

// ---------------- build concat([xw, broadcast(xf_p)]) -> bf16 ----------------
__global__ __launch_bounds__(256) void build_xc_k(
    const float* __restrict__ xw, const float* __restrict__ xfp, u16* __restrict__ xc)
{
  int idx = blockIdx.x * 256 + threadIdx.x;
  int c = idx & 255, n = (idx >> 8) & 511, b = idx >> 17;
  float val = (n < 256) ? xw[((b << 8) + n) * 256 + c] : xfp[(b << 8) + c];
  xc[idx] = f2bf(val);
}

// ---------------- attmat stage1 ----------------
__global__ __launch_bounds__(256) void attmat1_k(
    const float* __restrict__ ckp, const float* __restrict__ cvp, float* __restrict__ attp)
{
  __shared__ float a_s[64][68];
  __shared__ float b_s[64][68];
  int bh = blockIdx.x >> 3, sl = blockIdx.x & 7;
  int h = bh & 7, b = bh >> 3;
  int n0 = sl << 6;
  int tid = threadIdx.x;
  int d = tid & 63, lg = tid >> 6;
  float acc[16];
#pragma unroll
  for (int j = 0; j < 16; ++j) acc[j] = 0.f;
#pragma unroll
  for (int i = 0; i < 4; ++i) {
    int f = tid + (i << 8);
    int row = f >> 4, c4 = (f & 15) << 2;
    size_t src = ((size_t)(b * 512 + n0 + row)) * DD + h * 64 + c4;
    *(float4*)&a_s[row][c4] = *(const float4*)(ckp + src);
    *(float4*)&b_s[row][c4] = *(const float4*)(cvp + src);
  }
  __syncthreads();
  for (int nn = 0; nn < 64; ++nn) {
    float av = a_s[nn][d];
#pragma unroll
    for (int j4 = 0; j4 < 4; ++j4) {
      float4 b4 = *(float4*)&b_s[nn][lg * 16 + j4 * 4];
      acc[j4*4+0] = fmaf(av, b4.x, acc[j4*4+0]);
      acc[j4*4+1] = fmaf(av, b4.y, acc[j4*4+1]);
      acc[j4*4+2] = fmaf(av, b4.z, acc[j4*4+2]);
      acc[j4*4+3] = fmaf(av, b4.w, acc[j4*4+3]);
    }
  }
  float* op = attp + ((size_t)(bh * 8 + sl)) * 4096 + d * 64 + lg * 16;
#pragma unroll
  for (int j4 = 0; j4 < 4; ++j4)
    *(float4*)(op + j4 * 4) = make_float4(acc[j4*4+0], acc[j4*4+1], acc[j4*4+2], acc[j4*4+3]);
}

// ---------------- attmat stage2 ----------------
__global__ __launch_bounds__(256) void attred_k(
    const float* __restrict__ attp, float* __restrict__ att)
{
  int idx = (blockIdx.x * 256 + threadIdx.x) * 4;
  int bh = idx >> 12, e = idx & 4095;
  float4 s = make_float4(0.f, 0.f, 0.f, 0.f);
#pragma unroll
  for (int sl = 0; sl < 8; ++sl) {
    float4 v = *(const float4*)&attp[((size_t)(bh * 8 + sl)) * 4096 + e];
    s.x += v.x; s.y += v.y; s.z += v.z; s.w += v.w;
  }
  *(float4*)&att[idx] = s;
}

// ---------------- fused rowsum + sy: grid 64 (b*8+h) ----------------
__global__ __launch_bounds__(256) void sy3_k(
    const float* __restrict__ skp, const float* __restrict__ svp, float* __restrict__ sy)
{
  __shared__ float rsum[256];
  __shared__ float part[4][64];
  int b = blockIdx.x >> 3, h = blockIdx.x & 7;
  int t = threadIdx.x;
  int g16 = t >> 4, l16 = t & 15;
  for (int it = 0; it < 16; ++it) {
    int s = g16 * 16 + it;
    const float* base = skp + ((size_t)(b * 256 + s)) * 512 + h * 64;
    float4 v = *(const float4*)(base + l16 * 4);
    float sm = (v.x + v.y) + (v.z + v.w);
    sm += __shfl_xor(sm, 1); sm += __shfl_xor(sm, 2);
    sm += __shfl_xor(sm, 4); sm += __shfl_xor(sm, 8);
    if (l16 == 0) rsum[s] = sm;
  }
  __syncthreads();
  int li = t & 63, sg = t >> 6;
  float acc = 0.f;
  for (int j = 0; j < 64; ++j) {
    int s = sg * 64 + j;
    size_t ix = (size_t)(b * 256 + s);
    acc = fmaf(rsum[s], svp[ix * 512 + h * 64 + li], acc);
  }
  part[sg][li] = acc;
  __syncthreads();
  if (t < 64) sy[(b * 8 + h) * 64 + t] = (part[0][t] + part[1][t]) + (part[2][t] + part[3][t]);
}

// ---------------- out = silu(cq @ att + sy) bf16 ; cq is bf16 ----------------
__global__ __launch_bounds__(256) void cy_k(
    const u16* __restrict__ cq, const float* __restrict__ att,
    const float* __restrict__ sy, u16* __restrict__ out)
{
  __shared__ float atts[64][68];
  __shared__ float qs[64][68];
  __shared__ float sys[64];
  int blk = blockIdx.x;
  int tt = blk & 15, h = (blk >> 4) & 7, b = blk >> 7;
  int t0 = tt << 6;
  int tid = threadIdx.x;
#pragma unroll
  for (int i = 0; i < 4; ++i) {
    int f = tid + (i << 8);
    int row = f >> 4, c4 = (f & 15) << 2;
    *(float4*)&atts[row][c4] = *(const float4*)(att + (size_t)(b * 8 + h) * 4096 + row * 64 + c4);
    u16x4 qv4 = *(const u16x4*)(cq + ((size_t)(b * 1024 + t0 + row)) * DD + h * 64 + c4);
    qs[row][c4 + 0] = bf2f(qv4[0]);
    qs[row][c4 + 1] = bf2f(qv4[1]);
    qs[row][c4 + 2] = bf2f(qv4[2]);
    qs[row][c4 + 3] = bf2f(qv4[3]);
  }
  if (tid < 64) sys[tid] = sy[(b * 8 + h) * 64 + tid];
  __syncthreads();
  int r = tid >> 2, lg = tid & 3;
  float acc[16];
#pragma unroll
  for (int j = 0; j < 16; ++j) acc[j] = 0.f;
  for (int d = 0; d < 64; ++d) {
    float qv = qs[r][d];
#pragma unroll
    for (int j4 = 0; j4 < 4; ++j4) {
      float4 a4 = *(float4*)&atts[d][lg * 16 + j4 * 4];
      acc[j4*4+0] = fmaf(qv, a4.x, acc[j4*4+0]);
      acc[j4*4+1] = fmaf(qv, a4.y, acc[j4*4+1]);
      acc[j4*4+2] = fmaf(qv, a4.z, acc[j4*4+2]);
      acc[j4*4+3] = fmaf(qv, a4.w, acc[j4*4+3]);
    }
  }
  u16* op = out + ((size_t)(b * 1024 + t0 + r)) * DD + h * 64 + lg * 16;
#pragma unroll
  for (int j4 = 0; j4 < 4; ++j4) {
    u16x4 o4;
    o4[0] = f2bf(silu_f(acc[j4*4+0] + sys[lg * 16 + j4*4+0]));
    o4[1] = f2bf(silu_f(acc[j4*4+1] + sys[lg * 16 + j4*4+1]));
    o4[2] = f2bf(silu_f(acc[j4*4+2] + sys[lg * 16 + j4*4+2]));
    o4[3] = f2bf(silu_f(acc[j4*4+3] + sys[lg * 16 + j4*4+3]));
    *(u16x4*)(op + j4 * 4) = o4;
  }
}

// ---------------- fp32 -> bf16 elementwise convert ----------------
__global__ __launch_bounds__(256) void cvtf2b_k(const float* __restrict__ in, u16* __restrict__ out, int n)
{
  int i = (blockIdx.x * 256 + threadIdx.x) * 4;
  if (i >= n) return;
  float4 v = *(const float4*)(in + i);
  u16x4 o;
  o[0] = f2bf(v.x); o[1] = f2bf(v.y); o[2] = f2bf(v.z); o[3] = f2bf(v.w);
  *(u16x4*)(out + i) = o;
}

// ---------------- batched 512x512 transpose of 10 weights ----------------
struct W10 { const float* w[10]; u16* o[10]; };
__global__ __launch_bounds__(256) void wtrans10_k(W10 p)
{
  __shared__ float tile[32][33];
  int wi = blockIdx.x >> 8;
  int tb = blockIdx.x & 255;
  int tk = tb >> 4, tn = tb & 15;
  const float* W = p.w[wi];
  u16* Wt = p.o[wi];
  int lx = threadIdx.x & 31, ly = threadIdx.x >> 5;
#pragma unroll
  for (int i = 0; i < 4; ++i)
    tile[ly + 8 * i][lx] = W[(size_t)(tk * 32 + ly + 8 * i) * 512 + tn * 32 + lx];
  __syncthreads();
#pragma unroll
  for (int i = 0; i < 4; ++i)
    Wt[(size_t)(tn * 32 + ly + 8 * i) * 512 + tk * 32 + lx] = f2bf(tile[lx][ly + 8 * i]);
}

// ---------------- batched generic transpose of 4 weights (block-range dispatch) ----------------
struct WT4 { const float* w[4]; u16* o[4]; int kd[4]; int nd[4]; int base[4]; };
__global__ __launch_bounds__(256) void wtrans4_k(WT4 p)
{
  __shared__ float tile[32][33];
  int blk = blockIdx.x;
  int e = 3;
  if (blk < p.base[1]) e = 0;
  else if (blk < p.base[2]) e = 1;
  else if (blk < p.base[3]) e = 2;
  int idx = blk - p.base[e];
  const float* W = p.w[e];
  u16* Wt = p.o[e];
  int Kd = p.kd[e], Nd = p.nd[e];
  int ntn = Nd >> 5;
  int tk = idx / ntn, tn = idx % ntn;
  int lx = threadIdx.x & 31, ly = threadIdx.x >> 5;
#pragma unroll
  for (int i = 0; i < 4; ++i)
    tile[ly + 8 * i][lx] = W[(size_t)(tk * 32 + ly + 8 * i) * Nd + tn * 32 + lx];
  __syncthreads();
#pragma unroll
  for (int i = 0; i < 4; ++i)
    Wt[(size_t)(tn * 32 + ly + 8 * i) * Kd + tk * 32 + lx] = f2bf(tile[lx][ly + 8 * i]);
}

extern "C" void kernel_launch(void* const* d_in, const int* in_sizes, int n_in,
                              void* d_out, int out_size, void* d_ws, size_t ws_size,
                              hipStream_t stream)
{
  const float* x      = (const float*)d_in[0];
  const float* xf     = (const float*)d_in[1];
  const float* xw     = (const float*)d_in[2];
  const float* xs     = (const float*)d_in[3];
  const float* fp_w   = (const float*)d_in[4];
  const float* fp_b   = (const float*)d_in[5];
  const float* sa_ng  = (const float*)d_in[6];
  const float* sa_nb  = (const float*)d_in[7];
  const float* sa_qw  = (const float*)d_in[8];
  const float* sa_qb  = (const float*)d_in[9];
  const float* sa_kw  = (const float*)d_in[10];
  const float* sa_kb  = (const float*)d_in[11];
  const float* sa_vw  = (const float*)d_in[12];
  const float* sa_vb  = (const float*)d_in[13];
  const float* sa_ow  = (const float*)d_in[14];
  const float* sa_ob  = (const float*)d_in[15];
  const float* ca_ng  = (const float*)d_in[16];
  const float* ca_nb  = (const float*)d_in[17];
  const float* ca_tng = (const float*)d_in[18];
  const float* ca_tnb = (const float*)d_in[19];
  const float* ca_sng = (const float*)d_in[20];
  const float* ca_snb = (const float*)d_in[21];
  const float* ca_qw  = (const float*)d_in[22];
  const float* ca_qb  = (const float*)d_in[23];
  const float* ca_kw  = (const float*)d_in[24];
  const float* ca_kb  = (const float*)d_in[25];
  const float* ca_vw  = (const float*)d_in[26];
  const float* ca_vb  = (const float*)d_in[27];
  const float* ca_apw = (const float*)d_in[28];
  const float* ca_apb = (const float*)d_in[29];
  const float* ca_atw = (const float*)d_in[30];
  const float* ca_atb = (const float*)d_in[31];
  const float* ca_ow  = (const float*)d_in[32];
  const float* ca_ob  = (const float*)d_in[33];
  const float* an_g   = (const float*)d_in[34];
  const float* an_b   = (const float*)d_in[35];
  const float* ffn_w1 = (const float*)d_in[36];
  const float* ffn_b1 = (const float*)d_in[37];
  const float* ffn_w2 = (const float*)d_in[38];
  const float* ffn_b2 = (const float*)d_in[39];
  const float* ffn_ng = (const float*)d_in[40];
  const float* ffn_nb = (const float*)d_in[41];
  const float* ffn_ow = (const float*)d_in[42];
  const float* ffn_ob = (const float*)d_in[43];

  float* ws = (float*)d_ws;
  float* slotZ = ws;                       // Zb bf16 overlay: z1/cq/z2/h2/z3  (4M f)
  float* slotP = ws + 4194304;             // xp -> y1 -> y2               (4M f)
  u16* Zb = (u16*)slotZ;
  u16* S1 = (u16*)(ws + 8388608);          // xbf -> y1n -> hsb
  u16* S2 = (u16*)(ws + 10485760);         // xn  -> cys
  u16* S3 = (u16*)(ws + 12582912);         // qb  -> y2b
  u16* S4 = (u16*)(ws + 14680064);         // kb
  u16* Vt = (u16*)(ws + 16777216);         // V transposed [B*H*64][1024]
  u16* S6 = (u16*)(ws + 18874368);         // ao
  float* ck  = ws + 20971520;              // 2M f
  float* sk  = ws + 23068672;              // 1M f
  float* cv  = ws + 24117248;              // 2M f
  float* sv  = ws + 26214400;              // 1M f
  float* tnr = ws + 27262976;              // 2M f
  u16* tn = (u16*)(ws + 29360128);         // 2M bf16 (tn|sn contiguous 6144x512)
  u16* sn = (u16*)(ws + 30408704);         // 1M bf16
  u16* h1 = (u16*)(ws + 20971520);         // 16M bf16, aliases ck..tnr (dead by then)
  u16* xc = (u16*)(ws + 30932992);         // 1M bf16
  float* att = ws + 31457280;              // 256K f
  float* xfp = ws + 31719424;              // 2K f
  float* sy  = ws + 31723520;              // 4K f
  u16* wb = (u16*)(ws + 31727616);         // weights bf16 pool
  u16* fp_wt   = wb;
  u16* sa_qwt  = wb + 262144;
  u16* sa_kwt  = wb + 524288;
  u16* sa_vwt  = wb + 786432;
  u16* sa_owt  = wb + 1048576;
  u16* ca_qwt  = wb + 1310720;
  u16* ca_kwt  = wb + 1572864;
  u16* ca_vwt  = wb + 1835008;
  u16* ca_owt  = wb + 2097152;
  u16* ffn_owt = wb + 2359296;
  u16* ca_atwt = wb + 2621440;             // [512][256]
  u16* ffn_w1t = wb + 2752512;             // [2048][512]
  u16* ffn_w2t = wb + 3801088;             // [512][2048]
  u16* apwT    = wb + 4849664;             // [256][768]
  float* bQKV  = (float*)(wb + 5046272);   // 1536 f
  float* bKV   = bQKV + 1536;              // 1024 f
  float* attp  = ws + 34260992;            // 2M f

  dim3 blk(256);
  auto g64 = [](int M, int N) { return dim3((unsigned)(N >> 6), (unsigned)(M >> 6)); };

  // ---- conversions + bias concat ----
  cvtf2b_k<<<dim3(4096), blk, 0, stream>>>(x, S1, 4194304);
  W10 wp;
  wp.w[0] = fp_w;  wp.o[0] = fp_wt;
  wp.w[1] = sa_qw; wp.o[1] = sa_qwt;
  wp.w[2] = sa_kw; wp.o[2] = sa_kwt;
  wp.w[3] = sa_vw; wp.o[3] = sa_vwt;
  wp.w[4] = sa_ow; wp.o[4] = sa_owt;
  wp.w[5] = ca_qw; wp.o[5] = ca_qwt;
  wp.w[6] = ca_kw; wp.o[6] = ca_kwt;
  wp.w[7] = ca_vw; wp.o[7] = ca_vwt;
  wp.w[8] = ca_ow; wp.o[8] = ca_owt;
  wp.w[9] = ffn_ow; wp.o[9] = ffn_owt;
  wtrans10_k<<<dim3(2560), blk, 0, stream>>>(wp);
  WT4 wq;
  wq.w[0] = ca_atw; wq.o[0] = ca_atwt; wq.kd[0] = 256;  wq.nd[0] = 512;  wq.base[0] = 0;
  wq.w[1] = ffn_w1; wq.o[1] = ffn_w1t; wq.kd[1] = 512;  wq.nd[1] = 2048; wq.base[1] = 128;
  wq.w[2] = ffn_w2; wq.o[2] = ffn_w2t; wq.kd[2] = 2048; wq.nd[2] = 512;  wq.base[2] = 1152;
  wq.w[3] = ca_apw; wq.o[3] = apwT;    wq.kd[3] = 768;  wq.nd[3] = 256;  wq.base[3] = 2176;
  wtrans4_k<<<dim3(2368), blk, 0, stream>>>(wq);
  biascat_k<<<dim3(10), blk, 0, stream>>>(sa_qb, sa_kb, sa_vb, ca_kb, ca_vb, bQKV, bKV);

  // ---- text/audio cross-attn inputs ----
  xfp_k<<<dim3(512), blk, 0, stream>>>(xf, apwT, ca_apb, xfp);
  build_xc_k<<<dim3(4096), blk, 0, stream>>>(xw, xfp, xc);
  gemm64<0,0><<<g64(4096, 512), blk, 0, stream>>>(xc, ca_atwt, ca_atb, nullptr, 0.f, tnr, nullptr, nullptr, nullptr, 4096, 512, 256);
  ln_k<<<dim3(1024), blk, 0, stream>>>(tnr, ca_tng, ca_tnb, nullptr, tn, 4096, 0);
  ln_k<<<dim3(512), blk, 0, stream>>>(xs, ca_sng, ca_snb, nullptr, sn, 2048, 0);

  // ---- feat_proj + self-attention ----
  gemm64<0,0><<<g64(8192, 512), blk, 0, stream>>>(S1, fp_wt, fp_b, x, 1.f, slotP, nullptr, nullptr, nullptr, 8192, 512, 512); // xp (fp32)
  ln_k<<<dim3(2048), blk, 0, stream>>>(slotP, sa_ng, sa_nb, nullptr, S2, 8192, 0);                            // xn
  gemm64<0,3><<<g64(8192, 1536), blk, 0, stream>>>(S2, sa_qwt, bQKV, nullptr, 0.f, (float*)Vt, nullptr, S3, S4, 8192, 1536, 512); // Q,K,V^T
  attn4_k<<<dim3(512), blk, 0, stream>>>(S3, S4, Vt, S6);                                                     // ao=silu(attn)
  gemm64<0,5><<<g64(8192, 512), blk, 0, stream>>>(S6, sa_owt, sa_ob, slotP, 2.f, nullptr, nullptr, Zb, nullptr, 8192, 512, 512); // z1 (bf16)
  ln2_k<<<dim3(2048), blk, 0, stream>>>(Zb, an_g, an_b, ca_ng, ca_nb, slotP, S1, 8192);                       // y1 (fp32) + y1n (bf16)

  // ---- cross-attention ----
  gemm64<0,6><<<g64(8192, 512), blk, 0, stream>>>(S1, ca_qwt, ca_qb, nullptr, 0.f, nullptr, nullptr, Zb, nullptr, 8192, 512, 512); // cq = softmax(...) bf16
  gemm64<0,4><<<g64(6144, 1024), blk, 0, stream>>>(tn, ca_kwt, bKV, nullptr, 0.f, ck, cv, nullptr, nullptr, 6144, 1024, 512); // ck|sk, cv|sv
  smseq2_k<<<dim3(512), blk, 0, stream>>>(ck, sk);
  attmat1_k<<<dim3(512), blk, 0, stream>>>(ck, cv, attp);
  attred_k<<<dim3(256), blk, 0, stream>>>(attp, att);
  sy3_k<<<dim3(64), blk, 0, stream>>>(sk, sv, sy);
  cy_k<<<dim3(1024), blk, 0, stream>>>(Zb, att, sy, S2);                                                      // cys=silu(cy+sy)
  gemm64<0,5><<<g64(8192, 512), blk, 0, stream>>>(S2, ca_owt, ca_ob, slotP, 2.f, nullptr, nullptr, Zb, nullptr, 8192, 512, 512); // z2 (bf16)
  lnb_k<<<dim3(2048), blk, 0, stream>>>(Zb, an_g, an_b, slotP, S3, 8192, 0);                                  // y2 (fp32) + y2b (bf16)

  // ---- FFN ----
  gemm8w<1,1><<<dim3(8, 64), dim3(512), 0, stream>>>(S3, ffn_w1t, ffn_b1, nullptr, h1, 8192, 2048, 512);      // h1 = gelu(y2 @ W1)
  gemm64<0,1><<<g64(8192, 512), blk, 0, stream>>>(h1, ffn_w2t, ffn_b2, nullptr, 0.f, nullptr, nullptr, Zb, nullptr, 8192, 512, 2048); // h2 (bf16)
  lnb_k<<<dim3(2048), blk, 0, stream>>>(Zb, ffn_ng, ffn_nb, nullptr, S1, 8192, 1);                            // silu(LN(h2)) -> S1
  gemm64<0,5><<<g64(8192, 512), blk, 0, stream>>>(S1, ffn_owt, ffn_ob, slotP, 2.f, nullptr, nullptr, Zb, nullptr, 8192, 512, 512); // z3 (bf16)
  lnb_k<<<dim3(2048), blk, 0, stream>>>(Zb, an_g, an_b, (float*)d_out, nullptr, 8192, 0);                     // y3
}

// Round 19
// 329.983 us; speedup vs baseline: 1.1268x; 1.1268x over previous
//
#include <hip/hip_runtime.h>
#include <math.h>

typedef unsigned short u16;
typedef short s16x8 __attribute__((ext_vector_type(8)));
typedef float f32x4 __attribute__((ext_vector_type(4)));
typedef unsigned short u16x8 __attribute__((ext_vector_type(8)));
typedef unsigned short u16x4 __attribute__((ext_vector_type(4)));

#define DD 512

__device__ __forceinline__ float silu_f(float x) { return x / (1.f + __expf(-x)); }
__device__ __forceinline__ float gelu_f(float x) {
  float y = 1.5957691216f * (x + 0.044715f * x * x * x);
  return x / (1.f + __expf(-y));
}
__device__ __forceinline__ u16 f2bf(float f) {
  unsigned u = __float_as_uint(f);
  return (u16)((u + 0x7fffu + ((u >> 16) & 1u)) >> 16);
}
__device__ __forceinline__ float bf2f(u16 u) { return __uint_as_float(((unsigned)u) << 16); }
__device__ __forceinline__ unsigned cvtpk_bf16(float a, float b) {
  unsigned r;
  asm("v_cvt_pk_bf16_f32 %0, %1, %2" : "=v"(r) : "v"(a), "v"(b));
  return r;
}

__device__ __forceinline__ void gload16(const void* g, void* l) {
  __builtin_amdgcn_global_load_lds(
      (const __attribute__((address_space(1))) void*)(g),
      (__attribute__((address_space(3))) void*)(l), 16, 0, 0);
}

// ---------------- 64x64-tile bf16 GEMM, BK=64, XOR-swizzled LDS, 2-buf dbuf ----------------
// OB: 0 fp32 out (+res); 4 merged fp32 dual (N=1024); 3 merged QKV (N=1536);
//     1 plain bf16 out (ld=N); 5 bf16 out + fp32 res (ld=N);
//     6 bf16 out with fused per-64col softmax (head-aligned tiles, N==512, no-max exp)
template<int ACT, int OB>
__global__ __launch_bounds__(256) void gemm64(
    const u16* __restrict__ A, const u16* __restrict__ Bt,
    const float* __restrict__ bias, const float* __restrict__ res, float res_scale,
    float* __restrict__ outf, float* __restrict__ outf2,
    u16* __restrict__ outb, u16* __restrict__ outb2,
    int M, int N, int K)
{
  __shared__ u16 As[2][4096];
  __shared__ u16 Bs[2][4096];
  const int t = threadIdx.x, l = t & 63, w = t >> 6;
  const int gx = gridDim.x;
  const int nblk = gx * gridDim.y;
  const int id = blockIdx.y * gx + blockIdx.x;
  const int nid = (id & 7) * (nblk >> 3) + (id >> 3);
  const int bm = (nid / gx) << 6, bn = (nid % gx) << 6;
  const int wr = (w >> 1) << 5, wc = (w & 1) << 5;
  f32x4 acc[2][2];
#pragma unroll
  for (int i = 0; i < 2; ++i)
#pragma unroll
    for (int j = 0; j < 2; ++j) acc[i][j] = (f32x4){0.f, 0.f, 0.f, 0.f};

  auto stage = [&](int k0, int buf) {
#pragma unroll
    for (int i = 0; i < 2; ++i) {
      int c = t + (i << 8);
      int row = c >> 3, cq = c & 7;
      int cs = cq ^ (row & 7);
      gload16(A + (size_t)(bm + row) * K + k0 + cs * 8, (char*)As[buf] + (i << 12) + (w << 10));
      gload16(Bt + (size_t)(bn + row) * K + k0 + cs * 8, (char*)Bs[buf] + (i << 12) + (w << 10));
    }
  };
  stage(0, 0);
  asm volatile("s_waitcnt vmcnt(0)" ::: "memory");
  __builtin_amdgcn_s_barrier();

  const int fr = l & 15, q0 = l >> 4;
  const int nk = K >> 6;
  int cur = 0;
  for (int kt = 0; kt < nk; ++kt) {
    if (kt + 1 < nk) stage((kt + 1) << 6, cur ^ 1);
    s16x8 af[2][2], bg[2][2];
#pragma unroll
    for (int kk = 0; kk < 2; ++kk)
#pragma unroll
      for (int i = 0; i < 2; ++i) {
        int ra = wr + i * 16 + fr;
        af[kk][i] = *(const s16x8*)&As[cur][ra * 64 + (((q0 + kk * 4)) ^ (ra & 7)) * 8];
        int rb = wc + i * 16 + fr;
        bg[kk][i] = *(const s16x8*)&Bs[cur][rb * 64 + (((q0 + kk * 4)) ^ (rb & 7)) * 8];
      }
    asm volatile("s_waitcnt lgkmcnt(0)" ::: "memory");
    __builtin_amdgcn_sched_barrier(0);
#pragma unroll
    for (int kk = 0; kk < 2; ++kk)
#pragma unroll
      for (int mi = 0; mi < 2; ++mi)
#pragma unroll
        for (int ni = 0; ni < 2; ++ni)
          acc[mi][ni] = __builtin_amdgcn_mfma_f32_16x16x32_bf16(af[kk][mi], bg[kk][ni], acc[mi][ni], 0, 0, 0);
    asm volatile("s_waitcnt vmcnt(0)" ::: "memory");
    __builtin_amdgcn_s_barrier();
    cur ^= 1;
  }

  const int cr0 = (l >> 4) << 2, cc = l & 15;

  if (OB == 0 || OB == 4) {
    float* fdst = outf;
    int coff = bn, ld = N;
    if (OB == 4) { ld = 512; coff = bn & 511; if (bn >= 512) fdst = outf2; }
#pragma unroll
    for (int ni = 0; ni < 2; ++ni) {
      int n = bn + wc + ni * 16 + cc;
      int col = coff + wc + ni * 16 + cc;
      float bia = bias[n];
#pragma unroll
      for (int mi = 0; mi < 2; ++mi) {
#pragma unroll
        for (int r = 0; r < 4; ++r) {
          int m = bm + wr + mi * 16 + cr0 + r;
          size_t off = (size_t)m * ld + col;
          float o = acc[mi][ni][r] + bia;
          if (ACT == 1) o = gelu_f(o);
          if (res) o = fmaf(res_scale, res[off], o);
          fdst[off] = o;
        }
      }
    }
  } else if (OB == 1 || OB == 5) {
#pragma unroll
    for (int ni = 0; ni < 2; ++ni) {
      int n = bn + wc + ni * 16 + cc;
      float bia = bias[n];
#pragma unroll
      for (int mi = 0; mi < 2; ++mi) {
#pragma unroll
        for (int r = 0; r < 4; ++r) {
          int m = bm + wr + mi * 16 + cr0 + r;
          size_t off = (size_t)m * N + n;
          float o = acc[mi][ni][r] + bia;
          if (ACT == 1) o = gelu_f(o);
          if (OB == 5) o = fmaf(res_scale, res[off], o);
          outb[off] = f2bf(o);
        }
      }
    }
  } else if (OB == 6) {
    // fused head softmax -> bf16: tile's 64 cols == one head's softmax range.
    float* smem = (float*)&As[0][0];      // 128 floats
    float ev[2][2][4];
    float part[2][4];
#pragma unroll
    for (int mi = 0; mi < 2; ++mi)
#pragma unroll
      for (int r = 0; r < 4; ++r) part[mi][r] = 0.f;
#pragma unroll
    for (int ni = 0; ni < 2; ++ni) {
      float bia = bias[bn + wc + ni * 16 + cc];
#pragma unroll
      for (int mi = 0; mi < 2; ++mi)
#pragma unroll
        for (int r = 0; r < 4; ++r) {
          float e = __expf(acc[mi][ni][r] + bia);
          ev[mi][ni][r] = e;
          part[mi][r] += e;
        }
    }
#pragma unroll
    for (int mi = 0; mi < 2; ++mi)
#pragma unroll
      for (int r = 0; r < 4; ++r) {
        float s = part[mi][r];
        s += __shfl_xor(s, 1); s += __shfl_xor(s, 2);
        s += __shfl_xor(s, 4); s += __shfl_xor(s, 8);
        part[mi][r] = s;
      }
    __syncthreads();
#pragma unroll
    for (int mi = 0; mi < 2; ++mi)
#pragma unroll
      for (int r = 0; r < 4; ++r) {
        int trow = wr + mi * 16 + cr0 + r;
        smem[(w & 1) * 64 + trow] = part[mi][r];
      }
    __syncthreads();
#pragma unroll
    for (int mi = 0; mi < 2; ++mi)
#pragma unroll
      for (int r = 0; r < 4; ++r) {
        int trow = wr + mi * 16 + cr0 + r;
        float inv = 1.f / (smem[trow] + smem[64 + trow]);
#pragma unroll
        for (int ni = 0; ni < 2; ++ni) {
          int n = bn + wc + ni * 16 + cc;
          outb[(size_t)(bm + trow) * 512 + n] = f2bf(ev[mi][ni][r] * inv);
        }
      }
  } else {
    // OB == 3: merged QKV
    int seg = bn >> 9;
    int colbase = bn & 511;
    if (seg < 2) {
      u16* dst = seg ? outb2 : outb;
#pragma unroll
      for (int ni = 0; ni < 2; ++ni) {
        int col = colbase + wc + ni * 16 + cc;
        float bia = bias[bn + wc + ni * 16 + cc];
#pragma unroll
        for (int mi = 0; mi < 2; ++mi) {
#pragma unroll
          for (int r = 0; r < 4; ++r) {
            int m = bm + wr + mi * 16 + cr0 + r;
            dst[(size_t)m * 512 + col] = f2bf(acc[mi][ni][r] + bia);
          }
        }
      }
    } else {
      u16* tile = &As[0][0];
      __syncthreads();
#pragma unroll
      for (int ni = 0; ni < 2; ++ni) {
        int lc = wc + ni * 16 + cc;
        float bia = bias[bn + wc + ni * 16 + cc];
#pragma unroll
        for (int mi = 0; mi < 2; ++mi) {
          int lm0 = wr + mi * 16 + cr0;
          u16x4 pk;
#pragma unroll
          for (int r = 0; r < 4; ++r) pk[r] = f2bf(acc[mi][ni][r] + bia);
          *(u16x4*)&tile[lc * 64 + (lm0 ^ ((lc & 7) << 3))] = pk;
        }
      }
      __syncthreads();
      int h = colbase >> 6;
      size_t vrow0 = ((size_t)((bm >> 10) * 8 + h)) * 64;
      int d = t >> 3, c8 = (t & 7) << 3;
      *(u16x8*)(((u16*)outf) + (vrow0 + d) * 1024 + (bm & 1023) + c8) =
          *(u16x8*)&tile[d * 64 + (c8 ^ ((d & 7) << 3))];
    }
  }
}

// ---------------- 8-wave 128x256 tile GEMM (W1), BK=32, 4-chunk XOR swizzle ----------------
template<int ACT, int OBF>
__global__ __launch_bounds__(512) void gemm8w(
    const u16* __restrict__ A, const u16* __restrict__ Bt,
    const float* __restrict__ bias, float* __restrict__ outf, u16* __restrict__ outb,
    int M, int N, int K)
{
  __shared__ u16 As[2][4096];
  __shared__ u16 Bs[2][8192];
  const int t = threadIdx.x, l = t & 63, w = t >> 6;
  const int gx = gridDim.x;
  const int nblk = gx * gridDim.y;
  const int id = blockIdx.y * gx + blockIdx.x;
  const int nid = (id & 7) * (nblk >> 3) + (id >> 3);
  const int bm = (nid / gx) << 7, bn = (nid % gx) << 8;
  const int wr = (w >> 2) << 6, wc = (w & 3) << 6;
  f32x4 acc[4][4];
#pragma unroll
  for (int i = 0; i < 4; ++i)
#pragma unroll
    for (int j = 0; j < 4; ++j) acc[i][j] = (f32x4){0.f, 0.f, 0.f, 0.f};

  auto stage = [&](int k0, int buf) {
    {
      int row = t >> 2, cq = t & 3;
      int cs = cq ^ ((row >> 1) & 3);
      gload16(A + (size_t)(bm + row) * K + k0 + cs * 8, (char*)As[buf] + (w << 10));
    }
#pragma unroll
    for (int i = 0; i < 2; ++i) {
      int c = t + (i << 9);
      int row = c >> 2, cq = c & 3;
      int cs = cq ^ ((row >> 1) & 3);
      gload16(Bt + (size_t)(bn + row) * K + k0 + cs * 8, (char*)Bs[buf] + ((w + (i << 3)) << 10));
    }
  };
  stage(0, 0);
  asm volatile("s_waitcnt vmcnt(0)" ::: "memory");
  __builtin_amdgcn_s_barrier();

  const int fr = l & 15, q0 = l >> 4;
  const int nk = K >> 5;
  int cur = 0;
  for (int kt = 0; kt < nk; ++kt) {
    if (kt + 1 < nk) stage((kt + 1) << 5, cur ^ 1);
    s16x8 af[4], bg[4];
#pragma unroll
    for (int i = 0; i < 4; ++i) {
      int ra = wr + i * 16 + fr;
      af[i] = *(const s16x8*)&As[cur][ra * 32 + (q0 ^ ((ra >> 1) & 3)) * 8];
      int rb = wc + i * 16 + fr;
      bg[i] = *(const s16x8*)&Bs[cur][rb * 32 + (q0 ^ ((rb >> 1) & 3)) * 8];
    }
    asm volatile("s_waitcnt lgkmcnt(0)" ::: "memory");
    __builtin_amdgcn_sched_barrier(0);
#pragma unroll
    for (int mi = 0; mi < 4; ++mi)
#pragma unroll
      for (int ni = 0; ni < 4; ++ni)
        acc[mi][ni] = __builtin_amdgcn_mfma_f32_16x16x32_bf16(af[mi], bg[ni], acc[mi][ni], 0, 0, 0);
    asm volatile("s_waitcnt vmcnt(0)" ::: "memory");
    __builtin_amdgcn_s_barrier();
    cur ^= 1;
  }

  const int cr0 = (l >> 4) << 2, cc = l & 15;
#pragma unroll
  for (int ni = 0; ni < 4; ++ni) {
    int n = bn + wc + ni * 16 + cc;
    float bia = bias[n];
#pragma unroll
    for (int mi = 0; mi < 4; ++mi) {
#pragma unroll
      for (int r = 0; r < 4; ++r) {
        int m = bm + wr + mi * 16 + cr0 + r;
        size_t off = (size_t)m * N + n;
        float o = acc[mi][ni][r] + bia;
        if (ACT == 1) o = gelu_f(o);
        if (OBF) outb[off] = f2bf(o);
        else outf[off] = o;
      }
    }
  }
}

// ---------------- xf projection ----------------
__global__ __launch_bounds__(256) void xfp_k(
    const float* __restrict__ xf, const u16* __restrict__ apwT,
    const float* __restrict__ bias, float* __restrict__ xfp)
{
  int wid = blockIdx.x * 4 + (threadIdx.x >> 6);
  int lane = threadIdx.x & 63;
  int b = wid >> 8, n = wid & 255;
  const u16* wp = apwT + (size_t)n * 768;
  const float* xp = xf + (size_t)b * 768;
  float s = 0.f;
#pragma unroll
  for (int j = 0; j < 12; ++j) s = fmaf(xp[lane + j * 64], bf2f(wp[lane + j * 64]), s);
#pragma unroll
  for (int m = 1; m < 64; m <<= 1) s += __shfl_xor(s, m);
  if (lane == 0) xfp[wid] = s + bias[n];
}

// ---------------- concat biases ----------------
__global__ __launch_bounds__(256) void biascat_k(
    const float* __restrict__ qb, const float* __restrict__ kb, const float* __restrict__ vb,
    const float* __restrict__ ckb, const float* __restrict__ cvb,
    float* __restrict__ bQKV, float* __restrict__ bKV)
{
  int t = blockIdx.x * 256 + threadIdx.x;
  if (t < 512) bQKV[t] = qb[t];
  else if (t < 1024) bQKV[t] = kb[t - 512];
  else if (t < 1536) bQKV[t] = vb[t - 1024];
  else if (t < 2048) bKV[t - 1536] = ckb[t - 1536];
  else if (t < 2560) bKV[t - 1536] = cvb[t - 2048];
}

// ---------------- LayerNorm over D=512, fp32 input ----------------
__global__ __launch_bounds__(256) void ln_k(
    const float* __restrict__ src, const float* __restrict__ g,
    const float* __restrict__ b, float* __restrict__ out32, u16* __restrict__ out16,
    int rows, int do_silu)
{
  int lane = threadIdx.x & 63, wv = threadIdx.x >> 6;
  int row = (blockIdx.x << 2) + wv;
  if (row >= rows) return;
  const float* p = src + (size_t)row * DD;
  float4 v0 = *(const float4*)(p + lane * 4);
  float4 v1 = *(const float4*)(p + 256 + lane * 4);
  float s = v0.x + v0.y + v0.z + v0.w + v1.x + v1.y + v1.z + v1.w;
  float ss = v0.x*v0.x + v0.y*v0.y + v0.z*v0.z + v0.w*v0.w
           + v1.x*v1.x + v1.y*v1.y + v1.z*v1.z + v1.w*v1.w;
#pragma unroll
  for (int m = 1; m < 64; m <<= 1) { s += __shfl_xor(s, m); ss += __shfl_xor(ss, m); }
  float mean = s * (1.f / 512.f);
  float var = ss * (1.f / 512.f) - mean * mean;
  float rstd = rsqrtf(var + 1e-5f);
  float4 g0 = *(const float4*)(g + lane * 4);
  float4 g1 = *(const float4*)(g + 256 + lane * 4);
  float4 b0 = *(const float4*)(b + lane * 4);
  float4 b1 = *(const float4*)(b + 256 + lane * 4);
  float o[8];
  o[0] = (v0.x - mean) * rstd * g0.x + b0.x;
  o[1] = (v0.y - mean) * rstd * g0.y + b0.y;
  o[2] = (v0.z - mean) * rstd * g0.z + b0.z;
  o[3] = (v0.w - mean) * rstd * g0.w + b0.w;
  o[4] = (v1.x - mean) * rstd * g1.x + b1.x;
  o[5] = (v1.y - mean) * rstd * g1.y + b1.y;
  o[6] = (v1.z - mean) * rstd * g1.z + b1.z;
  o[7] = (v1.w - mean) * rstd * g1.w + b1.w;
  if (do_silu) {
#pragma unroll
    for (int j = 0; j < 8; ++j) o[j] = silu_f(o[j]);
  }
  if (out32) {
    *(float4*)(out32 + (size_t)row * DD + lane * 4) = make_float4(o[0], o[1], o[2], o[3]);
    *(float4*)(out32 + (size_t)row * DD + 256 + lane * 4) = make_float4(o[4], o[5], o[6], o[7]);
  }
  if (out16) {
    u16x4 h0, h1;
#pragma unroll
    for (int j = 0; j < 4; ++j) { h0[j] = f2bf(o[j]); h1[j] = f2bf(o[4 + j]); }
    *(u16x4*)(out16 + (size_t)row * DD + lane * 4) = h0;
    *(u16x4*)(out16 + (size_t)row * DD + 256 + lane * 4) = h1;
  }
}

// ---------------- LayerNorm over D=512, bf16 input ----------------
__global__ __launch_bounds__(256) void lnb_k(
    const u16* __restrict__ src, const float* __restrict__ g,
    const float* __restrict__ b, float* __restrict__ out32, u16* __restrict__ out16,
    int rows, int do_silu)
{
  int lane = threadIdx.x & 63, wv = threadIdx.x >> 6;
  int row = (blockIdx.x << 2) + wv;
  if (row >= rows) return;
  const u16* p = src + (size_t)row * DD;
  u16x4 a0 = *(const u16x4*)(p + lane * 4);
  u16x4 a1 = *(const u16x4*)(p + 256 + lane * 4);
  float v[8];
#pragma unroll
  for (int j = 0; j < 4; ++j) { v[j] = bf2f(a0[j]); v[4 + j] = bf2f(a1[j]); }
  float s = 0.f, ss = 0.f;
#pragma unroll
  for (int j = 0; j < 8; ++j) { s += v[j]; ss = fmaf(v[j], v[j], ss); }
#pragma unroll
  for (int m = 1; m < 64; m <<= 1) { s += __shfl_xor(s, m); ss += __shfl_xor(ss, m); }
  float mean = s * (1.f / 512.f);
  float var = ss * (1.f / 512.f) - mean * mean;
  float rstd = rsqrtf(var + 1e-5f);
  float4 g0 = *(const float4*)(g + lane * 4);
  float4 g1 = *(const float4*)(g + 256 + lane * 4);
  float4 b0 = *(const float4*)(b + lane * 4);
  float4 b1 = *(const float4*)(b + 256 + lane * 4);
  float o[8];
  o[0] = (v[0] - mean) * rstd * g0.x + b0.x;
  o[1] = (v[1] - mean) * rstd * g0.y + b0.y;
  o[2] = (v[2] - mean) * rstd * g0.z + b0.z;
  o[3] = (v[3] - mean) * rstd * g0.w + b0.w;
  o[4] = (v[4] - mean) * rstd * g1.x + b1.x;
  o[5] = (v[5] - mean) * rstd * g1.y + b1.y;
  o[6] = (v[6] - mean) * rstd * g1.z + b1.z;
  o[7] = (v[7] - mean) * rstd * g1.w + b1.w;
  if (do_silu) {
#pragma unroll
    for (int j = 0; j < 8; ++j) o[j] = silu_f(o[j]);
  }
  if (out32) {
    *(float4*)(out32 + (size_t)row * DD + lane * 4) = make_float4(o[0], o[1], o[2], o[3]);
    *(float4*)(out32 + (size_t)row * DD + 256 + lane * 4) = make_float4(o[4], o[5], o[6], o[7]);
  }
  if (out16) {
    u16x4 h0, h1;
#pragma unroll
    for (int j = 0; j < 4; ++j) { h0[j] = f2bf(o[j]); h1[j] = f2bf(o[4 + j]); }
    *(u16x4*)(out16 + (size_t)row * DD + lane * 4) = h0;
    *(u16x4*)(out16 + (size_t)row * DD + 256 + lane * 4) = h1;
  }
}

// ---------------- fused double-LN ----------------
__global__ __launch_bounds__(256) void ln2_k(
    const u16* __restrict__ src, const float* __restrict__ g1, const float* __restrict__ b1,
    const float* __restrict__ g2, const float* __restrict__ b2,
    float* __restrict__ out1, u16* __restrict__ out2, int rows)
{
  int lane = threadIdx.x & 63, wv = threadIdx.x >> 6;
  int row = (blockIdx.x << 2) + wv;
  if (row >= rows) return;
  const u16* p = src + (size_t)row * DD;
  u16x4 a0 = *(const u16x4*)(p + lane * 4);
  u16x4 a1 = *(const u16x4*)(p + 256 + lane * 4);
  float v[8];
#pragma unroll
  for (int j = 0; j < 4; ++j) { v[j] = bf2f(a0[j]); v[4 + j] = bf2f(a1[j]); }
  float s = 0.f, ss = 0.f;
#pragma unroll
  for (int j = 0; j < 8; ++j) { s += v[j]; ss = fmaf(v[j], v[j], ss); }
#pragma unroll
  for (int m = 1; m < 64; m <<= 1) { s += __shfl_xor(s, m); ss += __shfl_xor(ss, m); }
  float mean = s * (1.f / 512.f);
  float rstd = rsqrtf(ss * (1.f / 512.f) - mean * mean + 1e-5f);
  float4 G0 = *(const float4*)(g1 + lane * 4);
  float4 G1 = *(const float4*)(g1 + 256 + lane * 4);
  float4 B0 = *(const float4*)(b1 + lane * 4);
  float4 B1 = *(const float4*)(b1 + 256 + lane * 4);
  float y[8];
  y[0] = (v[0] - mean) * rstd * G0.x + B0.x;
  y[1] = (v[1] - mean) * rstd * G0.y + B0.y;
  y[2] = (v[2] - mean) * rstd * G0.z + B0.z;
  y[3] = (v[3] - mean) * rstd * G0.w + B0.w;
  y[4] = (v[4] - mean) * rstd * G1.x + B1.x;
  y[5] = (v[5] - mean) * rstd * G1.y + B1.y;
  y[6] = (v[6] - mean) * rstd * G1.z + B1.z;
  y[7] = (v[7] - mean) * rstd * G1.w + B1.w;
  *(float4*)(out1 + (size_t)row * DD + lane * 4) = make_float4(y[0], y[1], y[2], y[3]);
  *(float4*)(out1 + (size_t)row * DD + 256 + lane * 4) = make_float4(y[4], y[5], y[6], y[7]);
  float s2 = 0.f, ss2 = 0.f;
#pragma unroll
  for (int j = 0; j < 8; ++j) { s2 += y[j]; ss2 = fmaf(y[j], y[j], ss2); }
#pragma unroll
  for (int m = 1; m < 64; m <<= 1) { s2 += __shfl_xor(s2, m); ss2 += __shfl_xor(ss2, m); }
  float m2 = s2 * (1.f / 512.f);
  float r2 = rsqrtf(ss2 * (1.f / 512.f) - m2 * m2 + 1e-5f);
  float4 H0 = *(const float4*)(g2 + lane * 4);
  float4 H1 = *(const float4*)(g2 + 256 + lane * 4);
  float4 C0 = *(const float4*)(b2 + lane * 4);
  float4 C1 = *(const float4*)(b2 + 256 + lane * 4);
  u16x4 h0, h1;
  h0[0] = f2bf((y[0] - m2) * r2 * H0.x + C0.x);
  h0[1] = f2bf((y[1] - m2) * r2 * H0.y + C0.y);
  h0[2] = f2bf((y[2] - m2) * r2 * H0.z + C0.z);
  h0[3] = f2bf((y[3] - m2) * r2 * H0.w + C0.w);
  h1[0] = f2bf((y[4] - m2) * r2 * H1.x + C1.x);
  h1[1] = f2bf((y[5] - m2) * r2 * H1.y + C1.y);
  h1[2] = f2bf((y[6] - m2) * r2 * H1.z + C1.z);
  h1[3] = f2bf((y[7] - m2) * r2 * H1.w + C1.w);
  *(u16x4*)(out2 + (size_t)row * DD + lane * 4) = h0;
  *(u16x4*)(out2 + (size_t)row * DD + 256 + lane * 4) = h1;
}

// ---------------- MFMA flash self-attention (XCD-chunked, cvt_pk P-pack) ----------------
__global__ __launch_bounds__(256) void attn3_k(
    const u16* __restrict__ q, const u16* __restrict__ k,
    const u16* __restrict__ vt, u16* __restrict__ out)
{
  __shared__ __align__(16) char KVb[2][2][8192];
  __shared__ __align__(16) char QP[16384];
  __shared__ float Lr[4][32];

  const int t = threadIdx.x, l = t & 63, w = t >> 6;
  const int id = blockIdx.x;
  const int blk = (id & 7) * 64 + (id >> 3);
  const int qt = blk & 7, h = (blk >> 3) & 7, b = blk >> 6;
  const size_t qbase = ((size_t)(b * 1024 + qt * 128)) * 512 + h * 64;
  const size_t kbase = ((size_t)(b * 1024)) * 512 + h * 64;
  const size_t vbase = ((size_t)((b * 8 + h) * 64)) * 1024;

#pragma unroll
  for (int i = 0; i < 4; ++i) {
    int chunk = i * 256 + w * 64 + l;
    int row = chunk >> 3, c = chunk & 7;
    int cs = c ^ (row & 7);
    gload16(q + qbase + (size_t)row * 512 + cs * 8, QP + (i * 256 + w * 64) * 16);
  }
  auto stageKV = [&](int st, int buf) {
#pragma unroll
    for (int i = 0; i < 2; ++i) {
      int chunk = i * 256 + w * 64 + l;
      int row = chunk >> 3, c = chunk & 7;
      int cs = c ^ (row & 7);
      gload16(k + kbase + (size_t)(st * 64 + row) * 512 + cs * 8,
              KVb[buf][0] + (i * 256 + w * 64) * 16);
      gload16(vt + vbase + (size_t)row * 1024 + st * 64 + cs * 8,
              KVb[buf][1] + (i * 256 + w * 64) * 16);
    }
  };
  stageKV(0, 0);
  __syncthreads();

  s16x8 qf[2][2];
#pragma unroll
  for (int ti = 0; ti < 2; ++ti)
#pragma unroll
    for (int kk = 0; kk < 2; ++kk) {
      int row = w * 32 + ti * 16 + (l & 15);
      int ch = ((l >> 4) + kk * 4) ^ (row & 7);
      qf[ti][kk] = *(const s16x8*)(QP + row * 128 + ch * 16);
    }

  f32x4 oacc[2][4];
#pragma unroll
  for (int qi = 0; qi < 2; ++qi)
#pragma unroll
    for (int dj = 0; dj < 4; ++dj) oacc[qi][dj] = (f32x4){0.f, 0.f, 0.f, 0.f};
  float lsum[2] = {0.f, 0.f};

  int cur = 0;
  for (int st = 0; st < 16; ++st) {
    if (st + 1 < 16) stageKV(st + 1, cur ^ 1);
    f32x4 sacc[4][2];
#pragma unroll
    for (int si = 0; si < 4; ++si)
#pragma unroll
      for (int ti = 0; ti < 2; ++ti) sacc[si][ti] = (f32x4){0.f, 0.f, 0.f, 0.f};
#pragma unroll
    for (int si = 0; si < 4; ++si) {
#pragma unroll
      for (int kk = 0; kk < 2; ++kk) {
        int s = si * 16 + (l & 15);
        int ch = ((l >> 4) + kk * 4) ^ (s & 7);
        s16x8 kf = *(const s16x8*)(KVb[cur][0] + s * 128 + ch * 16);
#pragma unroll
        for (int ti = 0; ti < 2; ++ti)
          sacc[si][ti] = __builtin_amdgcn_mfma_f32_16x16x32_bf16(kf, qf[ti][kk], sacc[si][ti], 0, 0, 0);
      }
    }
#pragma unroll
    for (int si = 0; si < 4; ++si)
#pragma unroll
      for (int ti = 0; ti < 2; ++ti) {
        float e0 = __expf(sacc[si][ti][0] * 0.125f);
        float e1 = __expf(sacc[si][ti][1] * 0.125f);
        float e2 = __expf(sacc[si][ti][2] * 0.125f);
        float e3 = __expf(sacc[si][ti][3] * 0.125f);
        lsum[ti] += (e0 + e1) + (e2 + e3);
        uint2 pk2;
        pk2.x = cvtpk_bf16(e0, e1);
        pk2.y = cvtpk_bf16(e2, e3);
        int tl = ti * 16 + (l & 15);
        int sb = (si * 16 + (l >> 4) * 4) * 2;
        *(uint2*)(QP + w * 4096 + tl * 128 + (sb ^ ((tl & 7) << 4))) = pk2;
      }
#pragma unroll
    for (int kk = 0; kk < 2; ++kk) {
      s16x8 pf[2];
#pragma unroll
      for (int qi = 0; qi < 2; ++qi) {
        int tl = qi * 16 + (l & 15);
        int ch = ((l >> 4) + kk * 4) ^ (tl & 7);
        pf[qi] = *(const s16x8*)(QP + w * 4096 + tl * 128 + ch * 16);
      }
#pragma unroll
      for (int dj = 0; dj < 4; ++dj) {
        int d = dj * 16 + (l & 15);
        int ch = ((l >> 4) + kk * 4) ^ (d & 7);
        s16x8 vf = *(const s16x8*)(KVb[cur][1] + d * 128 + ch * 16);
#pragma unroll
        for (int qi = 0; qi < 2; ++qi)
          oacc[qi][dj] = __builtin_amdgcn_mfma_f32_16x16x32_bf16(pf[qi], vf, oacc[qi][dj], 0, 0, 0);
      }
    }
    cur ^= 1;
    __syncthreads();
  }

#pragma unroll
  for (int ti = 0; ti < 2; ++ti) {
    lsum[ti] += __shfl_xor(lsum[ti], 16);
    lsum[ti] += __shfl_xor(lsum[ti], 32);
    Lr[w][ti * 16 + (l & 15)] = lsum[ti];
  }
  __syncthreads();
  u16* otile = (u16*)QP;
#pragma unroll
  for (int qi = 0; qi < 2; ++qi) {
    float linv[4];
#pragma unroll
    for (int r = 0; r < 4; ++r) linv[r] = 1.f / Lr[w][qi * 16 + (l >> 4) * 4 + r];
#pragma unroll
    for (int dj = 0; dj < 4; ++dj) {
#pragma unroll
      for (int r = 0; r < 4; ++r) {
        int trl = w * 32 + qi * 16 + (l >> 4) * 4 + r;
        otile[trl * 64 + dj * 16 + (l & 15)] = f2bf(silu_f(oacc[qi][dj][r] * linv[r]));
      }
    }
  }
  __syncthreads();
#pragma unroll
  for (int p = 0; p < 4; ++p) {
    int flat = p * 256 + t;
    int row = flat >> 3, c8 = (flat & 7) << 3;
    *(u16x8*)(out + ((size_t)(b * 1024 + qt * 128 + row)) * 512 + h * 64 + c8) =
        *(u16x8*)&otile[row * 64 + c8];
  }
}

// ---------------- merged seq-softmax: blocks 0..255 -> ck (NL=512), 256..511 -> sk (NL=256) ----------------
__device__ __forceinline__ void smseq_body(float* p, int b, int cg, int NL, int nj, int ci, float* red, int t)
{
  int col = cg * 16 + ci;
  float vals[32];
  float s = 0.f;
  int nit = NL / 16;
  for (int j = 0; j < nit; ++j) {
    float x = __expf(p[((size_t)(b * NL) + nj + j * 16) * 512 + col]);
    vals[j] = x; s += x;
  }
  red[t] = s;
  __syncthreads();
  float tot = 0.f;
#pragma unroll
  for (int j = 0; j < 16; ++j) tot += red[ci + j * 16];
  float inv = 1.f / tot;
  for (int j = 0; j < nit; ++j)
    p[((size_t)(b * NL) + nj + j * 16) * 512 + col] = vals[j] * inv;
}

__global__ __launch_bounds__(256) void smseq2_k(float* __restrict__ ck, float* __restrict__ sk)
{
  __shared__ float red[256];
  int t = threadIdx.x;
  int ci = t & 15, nj = t >> 4;
  if (blockIdx.x < 256) {
    int b = blockIdx.x >> 5, cg = blockIdx.x & 31;
    smseq_body(ck, b, cg, 512, nj, ci, red, t);
  } else {
    int blk = blockIdx.x - 256;
    int b = blk >> 5, cg = blk & 31;
    smseq_body(sk, b, cg, 256, nj, ci, red, t);
  }
}

// ---------------- build concat([xw, broadcast(xf_p)]) -> bf16 ----------------
__global__ __launch_bounds__(256) void build_xc_k(
    const float* __restrict__ xw, const float* __restrict__ xfp, u16* __restrict__ xc)
{
  int idx = blockIdx.x * 256 + threadIdx.x;
  int c = idx & 255, n = (idx >> 8) & 511, b = idx >> 17;
  float val = (n < 256) ? xw[((b << 8) + n) * 256 + c] : xfp[(b << 8) + c];
  xc[idx] = f2bf(val);
}

// ---------------- attmat stage1 ----------------
__global__ __launch_bounds__(256) void attmat1_k(
    const float* __restrict__ ckp, const float* __restrict__ cvp, float* __restrict__ attp)
{
  __shared__ float a_s[64][68];
  __shared__ float b_s[64][68];
  int bh = blockIdx.x >> 3, sl = blockIdx.x & 7;
  int h = bh & 7, b = bh >> 3;
  int n0 = sl << 6;
  int tid = threadIdx.x;
  int d = tid & 63, lg = tid >> 6;
  float acc[16];
#pragma unroll
  for (int j = 0; j < 16; ++j) acc[j] = 0.f;
#pragma unroll
  for (int i = 0; i < 4; ++i) {
    int f = tid + (i << 8);
    int row = f >> 4, c4 = (f & 15) << 2;
    size_t src = ((size_t)(b * 512 + n0 + row)) * DD + h * 64 + c4;
    *(float4*)&a_s[row][c4] = *(const float4*)(ckp + src);
    *(float4*)&b_s[row][c4] = *(const float4*)(cvp + src);
  }
  __syncthreads();
  for (int nn = 0; nn < 64; ++nn) {
    float av = a_s[nn][d];
#pragma unroll
    for (int j4 = 0; j4 < 4; ++j4) {
      float4 b4 = *(float4*)&b_s[nn][lg * 16 + j4 * 4];
      acc[j4*4+0] = fmaf(av, b4.x, acc[j4*4+0]);
      acc[j4*4+1] = fmaf(av, b4.y, acc[j4*4+1]);
      acc[j4*4+2] = fmaf(av, b4.z, acc[j4*4+2]);
      acc[j4*4+3] = fmaf(av, b4.w, acc[j4*4+3]);
    }
  }
  float* op = attp + ((size_t)(bh * 8 + sl)) * 4096 + d * 64 + lg * 16;
#pragma unroll
  for (int j4 = 0; j4 < 4; ++j4)
    *(float4*)(op + j4 * 4) = make_float4(acc[j4*4+0], acc[j4*4+1], acc[j4*4+2], acc[j4*4+3]);
}

// ---------------- attmat stage2 ----------------
__global__ __launch_bounds__(256) void attred_k(
    const float* __restrict__ attp, float* __restrict__ att)
{
  int idx = (blockIdx.x * 256 + threadIdx.x) * 4;
  int bh = idx >> 12, e = idx & 4095;
  float4 s = make_float4(0.f, 0.f, 0.f, 0.f);
#pragma unroll
  for (int sl = 0; sl < 8; ++sl) {
    float4 v = *(const float4*)&attp[((size_t)(bh * 8 + sl)) * 4096 + e];
    s.x += v.x; s.y += v.y; s.z += v.z; s.w += v.w;
  }
  *(float4*)&att[idx] = s;
}

// ---------------- fused rowsum + sy: grid 64 (b*8+h) ----------------
__global__ __launch_bounds__(256) void sy3_k(
    const float* __restrict__ skp, const float* __restrict__ svp, float* __restrict__ sy)
{
  __shared__ float rsum[256];
  __shared__ float part[4][64];
  int b = blockIdx.x >> 3, h = blockIdx.x & 7;
  int t = threadIdx.x;
  int g16 = t >> 4, l16 = t & 15;
  for (int it = 0; it < 16; ++it) {
    int s = g16 * 16 + it;
    const float* base = skp + ((size_t)(b * 256 + s)) * 512 + h * 64;
    float4 v = *(const float4*)(base + l16 * 4);
    float sm = (v.x + v.y) + (v.z + v.w);
    sm += __shfl_xor(sm, 1); sm += __shfl_xor(sm, 2);
    sm += __shfl_xor(sm, 4); sm += __shfl_xor(sm, 8);
    if (l16 == 0) rsum[s] = sm;
  }
  __syncthreads();
  int li = t & 63, sg = t >> 6;
  float acc = 0.f;
  for (int j = 0; j < 64; ++j) {
    int s = sg * 64 + j;
    size_t ix = (size_t)(b * 256 + s);
    acc = fmaf(rsum[s], svp[ix * 512 + h * 64 + li], acc);
  }
  part[sg][li] = acc;
  __syncthreads();
  if (t < 64) sy[(b * 8 + h) * 64 + t] = (part[0][t] + part[1][t]) + (part[2][t] + part[3][t]);
}

// ---------------- out = silu(cq @ att + sy) bf16 ; cq is bf16 ----------------
__global__ __launch_bounds__(256) void cy_k(
    const u16* __restrict__ cq, const float* __restrict__ att,
    const float* __restrict__ sy, u16* __restrict__ out)
{
  __shared__ float atts[64][68];
  __shared__ float qs[64][68];
  __shared__ float sys[64];
  int blk = blockIdx.x;
  int tt = blk & 15, h = (blk >> 4) & 7, b = blk >> 7;
  int t0 = tt << 6;
  int tid = threadIdx.x;
#pragma unroll
  for (int i = 0; i < 4; ++i) {
    int f = tid + (i << 8);
    int row = f >> 4, c4 = (f & 15) << 2;
    *(float4*)&atts[row][c4] = *(const float4*)(att + (size_t)(b * 8 + h) * 4096 + row * 64 + c4);
    u16x4 qv4 = *(const u16x4*)(cq + ((size_t)(b * 1024 + t0 + row)) * DD + h * 64 + c4);
    qs[row][c4 + 0] = bf2f(qv4[0]);
    qs[row][c4 + 1] = bf2f(qv4[1]);
    qs[row][c4 + 2] = bf2f(qv4[2]);
    qs[row][c4 + 3] = bf2f(qv4[3]);
  }
  if (tid < 64) sys[tid] = sy[(b * 8 + h) * 64 + tid];
  __syncthreads();
  int r = tid >> 2, lg = tid & 3;
  float acc[16];
#pragma unroll
  for (int j = 0; j < 16; ++j) acc[j] = 0.f;
  for (int d = 0; d < 64; ++d) {
    float qv = qs[r][d];
#pragma unroll
    for (int j4 = 0; j4 < 4; ++j4) {
      float4 a4 = *(float4*)&atts[d][lg * 16 + j4 * 4];
      acc[j4*4+0] = fmaf(qv, a4.x, acc[j4*4+0]);
      acc[j4*4+1] = fmaf(qv, a4.y, acc[j4*4+1]);
      acc[j4*4+2] = fmaf(qv, a4.z, acc[j4*4+2]);
      acc[j4*4+3] = fmaf(qv, a4.w, acc[j4*4+3]);
    }
  }
  u16* op = out + ((size_t)(b * 1024 + t0 + r)) * DD + h * 64 + lg * 16;
#pragma unroll
  for (int j4 = 0; j4 < 4; ++j4) {
    u16x4 o4;
    o4[0] = f2bf(silu_f(acc[j4*4+0] + sys[lg * 16 + j4*4+0]));
    o4[1] = f2bf(silu_f(acc[j4*4+1] + sys[lg * 16 + j4*4+1]));
    o4[2] = f2bf(silu_f(acc[j4*4+2] + sys[lg * 16 + j4*4+2]));
    o4[3] = f2bf(silu_f(acc[j4*4+3] + sys[lg * 16 + j4*4+3]));
    *(u16x4*)(op + j4 * 4) = o4;
  }
}

// ---------------- fp32 -> bf16 elementwise convert ----------------
__global__ __launch_bounds__(256) void cvtf2b_k(const float* __restrict__ in, u16* __restrict__ out, int n)
{
  int i = (blockIdx.x * 256 + threadIdx.x) * 4;
  if (i >= n) return;
  float4 v = *(const float4*)(in + i);
  u16x4 o;
  o[0] = f2bf(v.x); o[1] = f2bf(v.y); o[2] = f2bf(v.z); o[3] = f2bf(v.w);
  *(u16x4*)(out + i) = o;
}

// ---------------- batched 512x512 transpose of 10 weights ----------------
struct W10 { const float* w[10]; u16* o[10]; };
__global__ __launch_bounds__(256) void wtrans10_k(W10 p)
{
  __shared__ float tile[32][33];
  int wi = blockIdx.x >> 8;
  int tb = blockIdx.x & 255;
  int tk = tb >> 4, tn = tb & 15;
  const float* W = p.w[wi];
  u16* Wt = p.o[wi];
  int lx = threadIdx.x & 31, ly = threadIdx.x >> 5;
#pragma unroll
  for (int i = 0; i < 4; ++i)
    tile[ly + 8 * i][lx] = W[(size_t)(tk * 32 + ly + 8 * i) * 512 + tn * 32 + lx];
  __syncthreads();
#pragma unroll
  for (int i = 0; i < 4; ++i)
    Wt[(size_t)(tn * 32 + ly + 8 * i) * 512 + tk * 32 + lx] = f2bf(tile[lx][ly + 8 * i]);
}

// ---------------- batched generic transpose of 4 weights (block-range dispatch) ----------------
struct WT4 { const float* w[4]; u16* o[4]; int kd[4]; int nd[4]; int base[4]; };
__global__ __launch_bounds__(256) void wtrans4_k(WT4 p)
{
  __shared__ float tile[32][33];
  int blk = blockIdx.x;
  int e = 3;
  if (blk < p.base[1]) e = 0;
  else if (blk < p.base[2]) e = 1;
  else if (blk < p.base[3]) e = 2;
  int idx = blk - p.base[e];
  const float* W = p.w[e];
  u16* Wt = p.o[e];
  int Kd = p.kd[e], Nd = p.nd[e];
  int ntn = Nd >> 5;
  int tk = idx / ntn, tn = idx % ntn;
  int lx = threadIdx.x & 31, ly = threadIdx.x >> 5;
#pragma unroll
  for (int i = 0; i < 4; ++i)
    tile[ly + 8 * i][lx] = W[(size_t)(tk * 32 + ly + 8 * i) * Nd + tn * 32 + lx];
  __syncthreads();
#pragma unroll
  for (int i = 0; i < 4; ++i)
    Wt[(size_t)(tn * 32 + ly + 8 * i) * Kd + tk * 32 + lx] = f2bf(tile[lx][ly + 8 * i]);
}

extern "C" void kernel_launch(void* const* d_in, const int* in_sizes, int n_in,
                              void* d_out, int out_size, void* d_ws, size_t ws_size,
                              hipStream_t stream)
{
  const float* x      = (const float*)d_in[0];
  const float* xf     = (const float*)d_in[1];
  const float* xw     = (const float*)d_in[2];
  const float* xs     = (const float*)d_in[3];
  const float* fp_w   = (const float*)d_in[4];
  const float* fp_b   = (const float*)d_in[5];
  const float* sa_ng  = (const float*)d_in[6];
  const float* sa_nb  = (const float*)d_in[7];
  const float* sa_qw  = (const float*)d_in[8];
  const float* sa_qb  = (const float*)d_in[9];
  const float* sa_kw  = (const float*)d_in[10];
  const float* sa_kb  = (const float*)d_in[11];
  const float* sa_vw  = (const float*)d_in[12];
  const float* sa_vb  = (const float*)d_in[13];
  const float* sa_ow  = (const float*)d_in[14];
  const float* sa_ob  = (const float*)d_in[15];
  const float* ca_ng  = (const float*)d_in[16];
  const float* ca_nb  = (const float*)d_in[17];
  const float* ca_tng = (const float*)d_in[18];
  const float* ca_tnb = (const float*)d_in[19];
  const float* ca_sng = (const float*)d_in[20];
  const float* ca_snb = (const float*)d_in[21];
  const float* ca_qw  = (const float*)d_in[22];
  const float* ca_qb  = (const float*)d_in[23];
  const float* ca_kw  = (const float*)d_in[24];
  const float* ca_kb  = (const float*)d_in[25];
  const float* ca_vw  = (const float*)d_in[26];
  const float* ca_vb  = (const float*)d_in[27];
  const float* ca_apw = (const float*)d_in[28];
  const float* ca_apb = (const float*)d_in[29];
  const float* ca_atw = (const float*)d_in[30];
  const float* ca_atb = (const float*)d_in[31];
  const float* ca_ow  = (const float*)d_in[32];
  const float* ca_ob  = (const float*)d_in[33];
  const float* an_g   = (const float*)d_in[34];
  const float* an_b   = (const float*)d_in[35];
  const float* ffn_w1 = (const float*)d_in[36];
  const float* ffn_b1 = (const float*)d_in[37];
  const float* ffn_w2 = (const float*)d_in[38];
  const float* ffn_b2 = (const float*)d_in[39];
  const float* ffn_ng = (const float*)d_in[40];
  const float* ffn_nb = (const float*)d_in[41];
  const float* ffn_ow = (const float*)d_in[42];
  const float* ffn_ob = (const float*)d_in[43];

  float* ws = (float*)d_ws;
  float* slotZ = ws;                       // Zb bf16 overlay: z1/cq/z2/h2/z3  (4M f)
  float* slotP = ws + 4194304;             // xp -> y1 -> y2               (4M f)
  u16* Zb = (u16*)slotZ;
  u16* S1 = (u16*)(ws + 8388608);          // xbf -> y1n -> hsb
  u16* S2 = (u16*)(ws + 10485760);         // xn  -> cys
  u16* S3 = (u16*)(ws + 12582912);         // qb  -> y2b
  u16* S4 = (u16*)(ws + 14680064);         // kb
  u16* Vt = (u16*)(ws + 16777216);         // V transposed [B*H*64][1024]
  u16* S6 = (u16*)(ws + 18874368);         // ao
  float* ck  = ws + 20971520;              // 2M f
  float* sk  = ws + 23068672;              // 1M f
  float* cv  = ws + 24117248;              // 2M f
  float* sv  = ws + 26214400;              // 1M f
  float* tnr = ws + 27262976;              // 2M f
  u16* tn = (u16*)(ws + 29360128);         // 2M bf16 (tn|sn contiguous 6144x512)
  u16* sn = (u16*)(ws + 30408704);         // 1M bf16
  u16* h1 = (u16*)(ws + 20971520);         // 16M bf16, aliases ck..tnr (dead by then)
  u16* xc = (u16*)(ws + 30932992);         // 1M bf16
  float* att = ws + 31457280;              // 256K f
  float* xfp = ws + 31719424;              // 2K f
  float* sy  = ws + 31723520;              // 4K f
  u16* wb = (u16*)(ws + 31727616);         // weights bf16 pool
  u16* fp_wt   = wb;
  u16* sa_qwt  = wb + 262144;
  u16* sa_kwt  = wb + 524288;
  u16* sa_vwt  = wb + 786432;
  u16* sa_owt  = wb + 1048576;
  u16* ca_qwt  = wb + 1310720;
  u16* ca_kwt  = wb + 1572864;
  u16* ca_vwt  = wb + 1835008;
  u16* ca_owt  = wb + 2097152;
  u16* ffn_owt = wb + 2359296;
  u16* ca_atwt = wb + 2621440;             // [512][256]
  u16* ffn_w1t = wb + 2752512;             // [2048][512]
  u16* ffn_w2t = wb + 3801088;             // [512][2048]
  u16* apwT    = wb + 4849664;             // [256][768]
  float* bQKV  = (float*)(wb + 5046272);   // 1536 f
  float* bKV   = bQKV + 1536;              // 1024 f
  float* attp  = ws + 34260992;            // 2M f

  dim3 blk(256);
  auto g64 = [](int M, int N) { return dim3((unsigned)(N >> 6), (unsigned)(M >> 6)); };

  // ---- conversions + bias concat ----
  cvtf2b_k<<<dim3(4096), blk, 0, stream>>>(x, S1, 4194304);
  W10 wp;
  wp.w[0] = fp_w;  wp.o[0] = fp_wt;
  wp.w[1] = sa_qw; wp.o[1] = sa_qwt;
  wp.w[2] = sa_kw; wp.o[2] = sa_kwt;
  wp.w[3] = sa_vw; wp.o[3] = sa_vwt;
  wp.w[4] = sa_ow; wp.o[4] = sa_owt;
  wp.w[5] = ca_qw; wp.o[5] = ca_qwt;
  wp.w[6] = ca_kw; wp.o[6] = ca_kwt;
  wp.w[7] = ca_vw; wp.o[7] = ca_vwt;
  wp.w[8] = ca_ow; wp.o[8] = ca_owt;
  wp.w[9] = ffn_ow; wp.o[9] = ffn_owt;
  wtrans10_k<<<dim3(2560), blk, 0, stream>>>(wp);
  WT4 wq;
  wq.w[0] = ca_atw; wq.o[0] = ca_atwt; wq.kd[0] = 256;  wq.nd[0] = 512;  wq.base[0] = 0;
  wq.w[1] = ffn_w1; wq.o[1] = ffn_w1t; wq.kd[1] = 512;  wq.nd[1] = 2048; wq.base[1] = 128;
  wq.w[2] = ffn_w2; wq.o[2] = ffn_w2t; wq.kd[2] = 2048; wq.nd[2] = 512;  wq.base[2] = 1152;
  wq.w[3] = ca_apw; wq.o[3] = apwT;    wq.kd[3] = 768;  wq.nd[3] = 256;  wq.base[3] = 2176;
  wtrans4_k<<<dim3(2368), blk, 0, stream>>>(wq);
  biascat_k<<<dim3(10), blk, 0, stream>>>(sa_qb, sa_kb, sa_vb, ca_kb, ca_vb, bQKV, bKV);

  // ---- text/audio cross-attn inputs ----
  xfp_k<<<dim3(512), blk, 0, stream>>>(xf, apwT, ca_apb, xfp);
  build_xc_k<<<dim3(4096), blk, 0, stream>>>(xw, xfp, xc);
  gemm64<0,0><<<g64(4096, 512), blk, 0, stream>>>(xc, ca_atwt, ca_atb, nullptr, 0.f, tnr, nullptr, nullptr, nullptr, 4096, 512, 256);
  ln_k<<<dim3(1024), blk, 0, stream>>>(tnr, ca_tng, ca_tnb, nullptr, tn, 4096, 0);
  ln_k<<<dim3(512), blk, 0, stream>>>(xs, ca_sng, ca_snb, nullptr, sn, 2048, 0);

  // ---- feat_proj + self-attention ----
  gemm64<0,0><<<g64(8192, 512), blk, 0, stream>>>(S1, fp_wt, fp_b, x, 1.f, slotP, nullptr, nullptr, nullptr, 8192, 512, 512); // xp (fp32)
  ln_k<<<dim3(2048), blk, 0, stream>>>(slotP, sa_ng, sa_nb, nullptr, S2, 8192, 0);                            // xn
  gemm64<0,3><<<g64(8192, 1536), blk, 0, stream>>>(S2, sa_qwt, bQKV, nullptr, 0.f, (float*)Vt, nullptr, S3, S4, 8192, 1536, 512); // Q,K,V^T
  attn3_k<<<dim3(512), blk, 0, stream>>>(S3, S4, Vt, S6);                                                     // ao=silu(attn)
  gemm64<0,5><<<g64(8192, 512), blk, 0, stream>>>(S6, sa_owt, sa_ob, slotP, 2.f, nullptr, nullptr, Zb, nullptr, 8192, 512, 512); // z1 (bf16)
  ln2_k<<<dim3(2048), blk, 0, stream>>>(Zb, an_g, an_b, ca_ng, ca_nb, slotP, S1, 8192);                       // y1 (fp32) + y1n (bf16)

  // ---- cross-attention ----
  gemm64<0,6><<<g64(8192, 512), blk, 0, stream>>>(S1, ca_qwt, ca_qb, nullptr, 0.f, nullptr, nullptr, Zb, nullptr, 8192, 512, 512); // cq = softmax(...) bf16
  gemm64<0,4><<<g64(6144, 1024), blk, 0, stream>>>(tn, ca_kwt, bKV, nullptr, 0.f, ck, cv, nullptr, nullptr, 6144, 1024, 512); // ck|sk, cv|sv
  smseq2_k<<<dim3(512), blk, 0, stream>>>(ck, sk);
  attmat1_k<<<dim3(512), blk, 0, stream>>>(ck, cv, attp);
  attred_k<<<dim3(256), blk, 0, stream>>>(attp, att);
  sy3_k<<<dim3(64), blk, 0, stream>>>(sk, sv, sy);
  cy_k<<<dim3(1024), blk, 0, stream>>>(Zb, att, sy, S2);                                                      // cys=silu(cy+sy)
  gemm64<0,5><<<g64(8192, 512), blk, 0, stream>>>(S2, ca_owt, ca_ob, slotP, 2.f, nullptr, nullptr, Zb, nullptr, 8192, 512, 512); // z2 (bf16)
  lnb_k<<<dim3(2048), blk, 0, stream>>>(Zb, an_g, an_b, slotP, S3, 8192, 0);                                  // y2 (fp32) + y2b (bf16)

  // ---- FFN ----
  gemm8w<1,1><<<dim3(8, 64), dim3(512), 0, stream>>>(S3, ffn_w1t, ffn_b1, nullptr, h1, 8192, 2048, 512);      // h1 = gelu(y2 @ W1)
  gemm64<0,1><<<g64(8192, 512), blk, 0, stream>>>(h1, ffn_w2t, ffn_b2, nullptr, 0.f, nullptr, nullptr, Zb, nullptr, 8192, 512, 2048); // h2 (bf16)
  lnb_k<<<dim3(2048), blk, 0, stream>>>(Zb, ffn_ng, ffn_nb, nullptr, S1, 8192, 1);                            // silu(LN(h2)) -> S1
  gemm64<0,5><<<g64(8192, 512), blk, 0, stream>>>(S1, ffn_owt, ffn_ob, slotP, 2.f, nullptr, nullptr, Zb, nullptr, 8192, 512, 512); // z3 (bf16)
  lnb_k<<<dim3(2048), blk, 0, stream>>>(Zb, an_g, an_b, (float*)d_out, nullptr, 8192, 0);                     // y3
}